// Round 1
// 1120.180 us; speedup vs baseline: 1.2572x; 1.2572x over previous
//
#include <hip/hip_runtime.h>
#include <stdint.h>

typedef unsigned short u16;   // raw bf16 bits
typedef __attribute__((ext_vector_type(8))) short bf16x8;
typedef __attribute__((ext_vector_type(4))) float f32x4;

#define NB   4
#define NC   512
#define NC8  64
#define NH   128
#define NW   128
#define NHW  16384

__device__ __forceinline__ float b2f(u16 u) {
  union { float f; uint32_t i; } x; x.i = ((uint32_t)u) << 16; return x.f;
}
__device__ __forceinline__ u16 f2b(float f) {
  union { float f; uint32_t u; } x; x.f = f;
  uint32_t r = x.u + 0x7FFF + ((x.u >> 16) & 1);
  return (u16)(r >> 16);
}
__device__ __forceinline__ void load8bf(const u16* __restrict__ p, float* f) {
  uint4 u = *reinterpret_cast<const uint4*>(p);
  f[0] = b2f((u16)(u.x & 0xFFFF)); f[1] = b2f((u16)(u.x >> 16));
  f[2] = b2f((u16)(u.y & 0xFFFF)); f[3] = b2f((u16)(u.y >> 16));
  f[4] = b2f((u16)(u.z & 0xFFFF)); f[5] = b2f((u16)(u.z >> 16));
  f[6] = b2f((u16)(u.w & 0xFFFF)); f[7] = b2f((u16)(u.w >> 16));
}
__device__ __forceinline__ uint4 pack8bf(const float* f) {
  uint4 u;
  u.x = (uint32_t)f2b(f[0]) | ((uint32_t)f2b(f[1]) << 16);
  u.y = (uint32_t)f2b(f[2]) | ((uint32_t)f2b(f[3]) << 16);
  u.z = (uint32_t)f2b(f[4]) | ((uint32_t)f2b(f[5]) << 16);
  u.w = (uint32_t)f2b(f[6]) | ((uint32_t)f2b(f[7]) << 16);
  return u;
}

// ---------------------------------------------------------------------------
// K0a: convert Wv (512x512 fp32) -> bf16, same [o][c] layout.
__global__ __launch_bounds__(256) void convert_w(const float* __restrict__ W,
                                                 u16* __restrict__ Wb) {
  int i = (blockIdx.x * 256 + threadIdx.x) * 8;
  float4 a = *reinterpret_cast<const float4*>(W + i);
  float4 b = *reinterpret_cast<const float4*>(W + i + 4);
  float f[8] = {a.x, a.y, a.z, a.w, b.x, b.y, b.z, b.w};
  *reinterpret_cast<uint4*>(Wb + i) = pack8bf(f);
}

// ---------------------------------------------------------------------------
// K0b: xe (b, c=512, hw=16384) fp32 -> xeT (b, hw, c) bf16  (K-contiguous for MFMA)
__global__ __launch_bounds__(256) void transpose_cvt(const float* __restrict__ x,
                                                     u16* __restrict__ xT) {
  __shared__ float tile[32][33];
  int b = blockIdx.z;
  int c0 = blockIdx.y * 32;     // 16 tiles
  int n0 = blockIdx.x * 32;     // 512 tiles
  int tx = threadIdx.x & 31, ty = threadIdx.x >> 5;
  const float* src = x + ((size_t)b * NC + c0) * NHW + n0;
  for (int k = 0; k < 4; k++)
    tile[ty + k * 8][tx] = src[(size_t)(ty + k * 8) * NHW + tx];
  __syncthreads();
  u16* dst = xT + ((size_t)b * NHW + n0) * NC + c0;
  for (int k = 0; k < 4; k++) {
    int n = ty + k * 8;
    dst[(size_t)n * NC + tx] = f2b(tile[tx][n]);
  }
}

// ---------------------------------------------------------------------------
// K1: 64-channel projection (q or k):  y[b,o,hw] = sum_c W[o,c] x[b,c,hw] + bias[o]
// grid (hw_tiles=128, b=4), block 256.  hw tile = 128 (one h row).
__global__ __launch_bounds__(256) void proj64(const float* __restrict__ x,
                                              const float* __restrict__ Wt,
                                              const float* __restrict__ bias,
                                              u16* __restrict__ y) {
  int b = blockIdx.y;
  int hw0 = blockIdx.x * 128;
  __shared__ float xs[32][128];   // [cc][w]
  __shared__ float ws[64][32];    // [o][cc]
  int t = threadIdx.x;
  int og = t >> 5;      // 0..7  (8 o per group)
  int wl = t & 31;      // 0..31 (4 w each)
  float acc[8][4];
  for (int i = 0; i < 8; i++) for (int j = 0; j < 4; j++) acc[i][j] = 0.f;
  const float* xb = x + (size_t)b * NC * NHW + hw0;
  for (int c0 = 0; c0 < NC; c0 += 32) {
    for (int i = 0; i < 4; i++) {                 // 1024 float4 loads of x
      int idx4 = t + i * 256;
      int cc = idx4 >> 5, w4 = (idx4 & 31) * 4;
      float4 v = *reinterpret_cast<const float4*>(&xb[(size_t)(c0 + cc) * NHW + w4]);
      xs[cc][w4 + 0] = v.x; xs[cc][w4 + 1] = v.y; xs[cc][w4 + 2] = v.z; xs[cc][w4 + 3] = v.w;
    }
    for (int i = 0; i < 2; i++) {                 // 512 float4 loads of W
      int idx4 = t + i * 256;
      int o = idx4 >> 3, cb4 = (idx4 & 7) * 4;
      float4 v = *reinterpret_cast<const float4*>(&Wt[(size_t)o * NC + c0 + cb4]);
      ws[o][cb4 + 0] = v.x; ws[o][cb4 + 1] = v.y; ws[o][cb4 + 2] = v.z; ws[o][cb4 + 3] = v.w;
    }
    __syncthreads();
    for (int cc = 0; cc < 32; cc++) {
      float a[8], bb[4];
      for (int i = 0; i < 8; i++) a[i] = ws[og * 8 + i][cc];
      for (int j = 0; j < 4; j++) bb[j] = xs[cc][wl * 4 + j];
      for (int i = 0; i < 8; i++)
        for (int j = 0; j < 4; j++) acc[i][j] += a[i] * bb[j];
    }
    __syncthreads();
  }
  for (int i = 0; i < 8; i++) {
    int o = og * 8 + i;
    float bv = bias[o];
    u16 tmp[4];
    for (int j = 0; j < 4; j++) tmp[j] = f2b(acc[i][j] + bv);
    uint2 pk;
    pk.x = (uint32_t)tmp[0] | ((uint32_t)tmp[1] << 16);
    pk.y = (uint32_t)tmp[2] | ((uint32_t)tmp[3] << 16);
    *reinterpret_cast<uint2*>(&y[(size_t)(b * NC8 + o) * NHW + hw0 + wl * 4]) = pk;
  }
}

// ---------------------------------------------------------------------------
// K2: 512-channel projection (v) via MFMA bf16.
//   C[o,n] = sum_c Wb[o,c] * xT[b,n,c], both operands K(c)-contiguous bf16.
//   BM=BN=128, BK=64; 4 waves in 2x2, wave tile 64x64 (4x4 frags of 16x16x32).
//   LDS rows are 128 B -> XOR-swizzle byte ^= ((row&7)<<4) on BOTH write & read
//   (G4 recipe) so fragment ds_read_b128 is the free 2-way pattern.
// grid (o_tiles=4, n_tiles=128, b=4): consecutive blocks share the B-tile (L2 reuse).
__global__ __launch_bounds__(256) void proj_v_mfma(const u16* __restrict__ xT,
                                                   const u16* __restrict__ Wb,
                                                   const float* __restrict__ bias,
                                                   u16* __restrict__ y) {
  __shared__ __align__(16) u16 smem[16384];        // As [0:8192) | Bs [8192:16384)
  char* AsB = (char*)smem;
  char* BsB = (char*)(smem + 8192);
  int o0 = blockIdx.x * 128, n0 = blockIdx.y * 128, b = blockIdx.z;
  int t = threadIdx.x;
  int wid = t >> 6, lane = t & 63;
  int wm = wid >> 1, wn = wid & 1;
  int l15 = lane & 15, lhi = lane >> 4;

  f32x4 acc[4][4];
#pragma unroll
  for (int m = 0; m < 4; m++)
#pragma unroll
    for (int n = 0; n < 4; n++)
#pragma unroll
      for (int r = 0; r < 4; r++) acc[m][n][r] = 0.f;

  const u16* Arow = Wb + (size_t)o0 * NC;
  const u16* Brow = xT + ((size_t)b * NHW + n0) * NC;

  for (int c0 = 0; c0 < NC; c0 += 64) {
    // stage 128x64 bf16 tiles of A and B (reg-staged, swizzled ds_write_b128)
#pragma unroll
    for (int p = 0; p < 4; p++) {
      int idx = t + p * 256;            // 0..1023
      int row = idx >> 3;               // 0..127
      int cb  = (idx & 7) * 8;          // elem offset in K
      int dst = row * 128 + ((cb * 2) ^ ((row & 7) << 4));
      bf16x8 av = *reinterpret_cast<const bf16x8*>(Arow + (size_t)row * NC + c0 + cb);
      *reinterpret_cast<bf16x8*>(AsB + dst) = av;
      bf16x8 bv = *reinterpret_cast<const bf16x8*>(Brow + (size_t)row * NC + c0 + cb);
      *reinterpret_cast<bf16x8*>(BsB + dst) = bv;
    }
    __syncthreads();
#pragma unroll
    for (int kk = 0; kk < 2; kk++) {
      int kbyte = kk * 64 + lhi * 16;   // lane's 8-elem K-slice of the 32-wide MFMA K
      bf16x8 af[4], bfr[4];
#pragma unroll
      for (int m = 0; m < 4; m++) {
        int row = wm * 64 + m * 16 + l15;
        af[m] = *reinterpret_cast<const bf16x8*>(AsB + row * 128 + (kbyte ^ ((row & 7) << 4)));
      }
#pragma unroll
      for (int n = 0; n < 4; n++) {
        int row = wn * 64 + n * 16 + l15;
        bfr[n] = *reinterpret_cast<const bf16x8*>(BsB + row * 128 + (kbyte ^ ((row & 7) << 4)));
      }
#pragma unroll
      for (int m = 0; m < 4; m++)
#pragma unroll
        for (int n = 0; n < 4; n++)
          acc[m][n] = __builtin_amdgcn_mfma_f32_16x16x32_bf16(af[m], bfr[n], acc[m][n], 0, 0, 0);
    }
    __syncthreads();
  }

  // epilogue: D layout col=lane&15 (n), row=(lane>>4)*4+r (o). Repack via LDS
  // (per-wave 64x64 bf16 = 8 KB) for coalesced 16 B global stores; add bias here.
  char* stage = (char*)smem + wid * 8192;
#pragma unroll
  for (int m = 0; m < 4; m++) {
#pragma unroll
    for (int r = 0; r < 4; r++) {
      int lrow = m * 16 + lhi * 4 + r;
      float bval = bias[o0 + wm * 64 + lrow];
#pragma unroll
      for (int n = 0; n < 4; n++) {
        int col = n * 16 + l15;
        *reinterpret_cast<u16*>(stage + lrow * 128 + col * 2) = f2b(acc[m][n][r] + bval);
      }
    }
  }
  __syncthreads();
#pragma unroll
  for (int s = 0; s < 8; s++) {
    int row  = s * 8 + (lane >> 3);
    int colb = (lane & 7) * 8;
    uint4 v = *reinterpret_cast<const uint4*>(stage + row * 128 + colb * 2);
    size_t addr = ((size_t)b * NC + o0 + wm * 64 + row) * (size_t)NHW + n0 + wn * 64 + colb;
    *reinterpret_cast<uint4*>(&y[addr]) = v;
  }
}

// ---------------------------------------------------------------------------
// K3: transpose last two dims of (planes,128,128) bf16 tensor
__global__ __launch_bounds__(256) void transpose128(const u16* __restrict__ src,
                                                    u16* __restrict__ dst) {
  __shared__ u16 tile[32][33];
  int p = blockIdx.z;
  int i0 = blockIdx.y * 32, j0 = blockIdx.x * 32;
  int tx = threadIdx.x & 31, ty = threadIdx.x >> 5;
  const u16* s = src + (size_t)p * NHW;
  u16* d = dst + (size_t)p * NHW;
  for (int k = 0; k < 4; k++) {
    int i = i0 + ty + k * 8;
    tile[ty + k * 8][tx] = s[(size_t)i * 128 + j0 + tx];
  }
  __syncthreads();
  for (int k = 0; k < 4; k++) {
    int j = j0 + ty + k * 8;
    d[(size_t)j * 128 + i0 + tx] = tile[tx][ty + k * 8];
  }
}

// ---------------------------------------------------------------------------
// K4: energy. For isH=0 (energy_W): block (s=h, b): e[w][j] = sum_c q[b,c,h,w] k[b,c,h,j]
//     For isH=1 (energy_H): pass q_sw,k_sw, s=w: e[h][j] = sum_c q[b,c,h,w] k[b,c,j,w], mask j==h
// att layout (B,H,W,256): [0:128)=eH, [128:256)=eW
__global__ __launch_bounds__(256) void energy_kern(const u16* __restrict__ Q,
                                                   const u16* __restrict__ K,
                                                   u16* __restrict__ att, int isH) {
  int b = blockIdx.y, s = blockIdx.x;
  __shared__ float qs[64][128];
  __shared__ float ks[64][128];
  int t = threadIdx.x;
  const u16* Qb = Q + (size_t)b * NC8 * NHW + s * 128;
  const u16* Kb = K + (size_t)b * NC8 * NHW + s * 128;
  for (int i = 0; i < 4; i++) {        // 8192 elems each, 8 at a time
    int idx8 = t + i * 256;
    int c = idx8 >> 4, x8 = (idx8 & 15) * 8;
    float f[8];
    load8bf(&Qb[(size_t)c * NHW + x8], f);
    for (int j = 0; j < 8; j++) qs[c][x8 + j] = f[j];
    load8bf(&Kb[(size_t)c * NHW + x8], f);
    for (int j = 0; j < 8; j++) ks[c][x8 + j] = f[j];
  }
  __syncthreads();
  int ty = t >> 4, tx = t & 15;
  float acc[8][8];
  for (int i = 0; i < 8; i++) for (int j = 0; j < 8; j++) acc[i][j] = 0.f;
  for (int c = 0; c < 64; c++) {
    float a[8], bb[8];
    for (int i = 0; i < 8; i++) a[i] = qs[c][ty * 8 + i];
    for (int j = 0; j < 8; j++) bb[j] = ks[c][tx * 8 + j];
    for (int i = 0; i < 8; i++)
      for (int j = 0; j < 8; j++) acc[i][j] += a[i] * bb[j];
  }
  size_t attb = (size_t)b * 4194304;
  for (int i = 0; i < 8; i++) {
    int r = ty * 8 + i;
    float row[8];
    for (int j = 0; j < 8; j++) {
      int jj = tx * 8 + j;
      float v = acc[i][j];
      if (isH && jj == r) v = -1e30f;
      row[j] = v;
    }
    size_t addr;
    if (isH) addr = attb + (size_t)r * 32768 + (size_t)s * 256 + tx * 8;
    else     addr = attb + (size_t)s * 32768 + (size_t)r * 256 + 128 + tx * 8;
    *reinterpret_cast<uint4*>(&att[addr]) = pack8bf(row);
  }
}

// ---------------------------------------------------------------------------
// K5: softmax over 256-entry rows, in place. One wave per row.
__global__ __launch_bounds__(256) void softmax_kern(u16* __restrict__ att) {
  int wave = threadIdx.x >> 6;
  int lane = threadIdx.x & 63;
  size_t row = (size_t)blockIdx.x * 4 + wave;
  u16* p = att + row * 256;
  uint2 u = *reinterpret_cast<const uint2*>(&p[lane * 4]);
  float v[4];
  v[0] = b2f((u16)(u.x & 0xFFFF)); v[1] = b2f((u16)(u.x >> 16));
  v[2] = b2f((u16)(u.y & 0xFFFF)); v[3] = b2f((u16)(u.y >> 16));
  float mx = fmaxf(fmaxf(v[0], v[1]), fmaxf(v[2], v[3]));
  for (int off = 32; off; off >>= 1) mx = fmaxf(mx, __shfl_xor(mx, off));
  float sum = 0.f;
  for (int i = 0; i < 4; i++) { v[i] = __expf(v[i] - mx); sum += v[i]; }
  for (int off = 32; off; off >>= 1) sum += __shfl_xor(sum, off);
  float inv = 1.f / sum;
  uint2 o;
  o.x = (uint32_t)f2b(v[0] * inv) | ((uint32_t)f2b(v[1] * inv) << 16);
  o.y = (uint32_t)f2b(v[2] * inv) | ((uint32_t)f2b(v[3] * inv) << 16);
  *reinterpret_cast<uint2*>(&p[lane * 4]) = o;
}

// ---------------------------------------------------------------------------
// K6: output GEMM.  block (ct, s, b): out[c][r] = sum_j V[b, ct*128+c, s*128+j] * Batt[r][j]
//   isH=0 (out_W): V=v natural, s=h, r=w, Batt row = att[b,s,r,128+j], out[b,c,h=s,w=r]
//   isH=1 (out_H): V=v_sw,      s=w, r=h, Batt row = att[b,r,s,j],     out_sw[b,c,w=s,h=r]
// out addr = b*8388608 + c_glob*16384 + s*128 + r   (same form both cases)
template <typename OT>
__global__ __launch_bounds__(256) void out_gemm(const u16* __restrict__ V,
                                                const u16* __restrict__ att,
                                                OT* __restrict__ out, int isH) {
  int ct = blockIdx.x, s = blockIdx.y, b = blockIdx.z;
  __shared__ float vs[128][17];
  __shared__ float bs[128][17];
  int t = threadIdx.x;
  int ty = t >> 4, tx = t & 15;
  float acc[8][8];
  for (int i = 0; i < 8; i++) for (int j = 0; j < 8; j++) acc[i][j] = 0.f;
  size_t attb = (size_t)b * 4194304;
  int rr = t >> 1, jb = (t & 1) * 8;
  const u16* vp = V + (size_t)(b * NC + ct * 128 + rr) * NHW + s * 128 + jb;
  for (int j0 = 0; j0 < 128; j0 += 16) {
    float f[8];
    load8bf(vp + j0, f);
    for (int i = 0; i < 8; i++) vs[rr][jb + i] = f[i];
    size_t arow = attb + (isH ? ((size_t)rr * 32768 + (size_t)s * 256)
                              : ((size_t)s * 32768 + (size_t)rr * 256 + 128)) + j0 + jb;
    load8bf(&att[arow], f);
    for (int i = 0; i < 8; i++) bs[rr][jb + i] = f[i];
    __syncthreads();
    for (int jj = 0; jj < 16; jj++) {
      float a[8], bb[8];
      for (int i = 0; i < 8; i++) a[i] = vs[ty * 8 + i][jj];
      for (int j = 0; j < 8; j++) bb[j] = bs[tx * 8 + j][jj];
      for (int i = 0; i < 8; i++)
        for (int j = 0; j < 8; j++) acc[i][j] += a[i] * bb[j];
    }
    __syncthreads();
  }
  for (int i = 0; i < 8; i++) {
    int c = ct * 128 + ty * 8 + i;
    size_t base = (size_t)b * 8388608 + (size_t)c * NHW + (size_t)s * 128 + tx * 8;
    for (int j = 0; j < 8; j++) {
      float v = acc[i][j];
      if constexpr (sizeof(OT) == 2) out[base + j] = f2b(v);
      else                           out[base + j] = v;
    }
  }
}

// ---------------------------------------------------------------------------
// K7: epilogue. out0 = g1*(outW + outH^T + 2) + xe ; out1 = g2*(...) + xq
// outW aliases out0 (same-index read then write by same thread -> safe).
__global__ __launch_bounds__(256) void epilogue(const float* outW,
                                                const u16* __restrict__ outHsw,
                                                const float* __restrict__ xe,
                                                const float* __restrict__ xq,
                                                const float* __restrict__ g1p,
                                                const float* __restrict__ g2p,
                                                float* out0, float* out1) {
  __shared__ float tile[32][33];
  int p = blockIdx.z;                 // b*512 + c
  int h0 = blockIdx.y * 32, w0 = blockIdx.x * 32;
  int tx = threadIdx.x & 31, ty = threadIdx.x >> 5;
  const u16* src = outHsw + (size_t)p * NHW;   // [w][h]
  for (int k = 0; k < 4; k++) {
    int w = w0 + ty + k * 8;
    tile[ty + k * 8][tx] = b2f(src[(size_t)w * 128 + h0 + tx]);
  }
  __syncthreads();
  float g1 = g1p[0], g2 = g2p[0];
  for (int k = 0; k < 4; k++) {
    int h = h0 + ty + k * 8;
    size_t idx = (size_t)p * NHW + (size_t)h * 128 + w0 + tx;
    float sum = outW[idx] + tile[tx][ty + k * 8] + 2.0f;
    out0[idx] = g1 * sum + xe[idx];
    out1[idx] = g2 * sum + xq[idx];
  }
}

// ---------------------------------------------------------------------------
extern "C" void kernel_launch(void* const* d_in, const int* in_sizes, int n_in,
                              void* d_out, int out_size, void* d_ws, size_t ws_size,
                              hipStream_t stream) {
  (void)in_sizes; (void)n_in; (void)out_size; (void)ws_size;
  const float* xe = (const float*)d_in[0];
  const float* xq = (const float*)d_in[1];
  const float* Wq = (const float*)d_in[2];
  const float* bq = (const float*)d_in[3];
  const float* Wk = (const float*)d_in[4];
  const float* bk = (const float*)d_in[5];
  const float* Wv = (const float*)d_in[6];
  const float* bv = (const float*)d_in[7];
  const float* g1 = (const float*)d_in[8];
  const float* g2 = (const float*)d_in[9];
  float* out = (float*)d_out;

  char* ws = (char*)d_ws;
  u16* q_n    = (u16*)(ws + 0);            //  8 MiB  (4,64,128,128)
  u16* k_n    = (u16*)(ws + 8388608);      //  8 MiB
  u16* q_sw   = (u16*)(ws + 16777216);     //  8 MiB  (b,c,w,h)
  u16* k_sw   = (u16*)(ws + 25165824);     //  8 MiB
  u16* v_n    = (u16*)(ws + 33554432);     // 64 MiB  (4,512,128,128)
  u16* v_sw   = (u16*)(ws + 100663296);    // 64 MiB
  u16* att    = (u16*)(ws + 167772160);    // 32 MiB  (4,128,128,256)
  u16* outHsw = (u16*)(ws + 201326592);    // 64 MiB  (b,c,w,h)
  // lifetime-overlapped scratch (dead regions at time of use):
  u16* wv_bf  = (u16*)(ws + 100663296);    // 512 KiB in v_sw slot (v_sw written later)
  u16* xeT    = (u16*)(ws + 201326592);    // 64 MiB in outHsw slot (written later)

  convert_w<<<dim3(128), 256, 0, stream>>>(Wv, wv_bf);
  transpose_cvt<<<dim3(512, 16, 4), 256, 0, stream>>>(xe, xeT);
  proj64<<<dim3(128, 4), 256, 0, stream>>>(xq, Wq, bq, q_n);
  proj64<<<dim3(128, 4), 256, 0, stream>>>(xe, Wk, bk, k_n);
  proj_v_mfma<<<dim3(4, 128, 4), 256, 0, stream>>>(xeT, wv_bf, bv, v_n);
  transpose128<<<dim3(4, 4, 256), 256, 0, stream>>>(q_n, q_sw);
  transpose128<<<dim3(4, 4, 256), 256, 0, stream>>>(k_n, k_sw);
  transpose128<<<dim3(4, 4, 2048), 256, 0, stream>>>(v_n, v_sw);
  energy_kern<<<dim3(128, 4), 256, 0, stream>>>(q_n, k_n, att, 0);
  energy_kern<<<dim3(128, 4), 256, 0, stream>>>(q_sw, k_sw, att, 1);
  softmax_kern<<<dim3(16384), 256, 0, stream>>>(att);
  out_gemm<float><<<dim3(4, 128, 4), 256, 0, stream>>>(v_n, att, out, 0);
  out_gemm<u16><<<dim3(4, 128, 4), 256, 0, stream>>>(v_sw, att, outHsw, 1);
  epilogue<<<dim3(4, 4, 2048), 256, 0, stream>>>(out, outHsw, xe, xq, g1, g2,
                                                 out, out + 33554432);
}

// Round 2
// 863.596 us; speedup vs baseline: 1.6308x; 1.2971x over previous
//
#include <hip/hip_runtime.h>
#include <stdint.h>

typedef unsigned short u16;   // raw bf16 bits
typedef __attribute__((ext_vector_type(8))) short bf16x8;
typedef __attribute__((ext_vector_type(4))) float f32x4;

#define NB   4
#define NC   512
#define NC8  64
#define NH   128
#define NW   128
#define NHW  16384

__device__ __forceinline__ float b2f(u16 u) {
  union { float f; uint32_t i; } x; x.i = ((uint32_t)u) << 16; return x.f;
}
__device__ __forceinline__ u16 f2b(float f) {
  union { float f; uint32_t u; } x; x.f = f;
  uint32_t r = x.u + 0x7FFF + ((x.u >> 16) & 1);
  return (u16)(r >> 16);
}
__device__ __forceinline__ uint4 pack8bf(const float* f) {
  uint4 u;
  u.x = (uint32_t)f2b(f[0]) | ((uint32_t)f2b(f[1]) << 16);
  u.y = (uint32_t)f2b(f[2]) | ((uint32_t)f2b(f[3]) << 16);
  u.z = (uint32_t)f2b(f[4]) | ((uint32_t)f2b(f[5]) << 16);
  u.w = (uint32_t)f2b(f[6]) | ((uint32_t)f2b(f[7]) << 16);
  return u;
}

// ---------------------------------------------------------------------------
// K0a: convert Wv (512x512 fp32) -> bf16, same [o][c] layout.
__global__ __launch_bounds__(256) void convert_w(const float* __restrict__ W,
                                                 u16* __restrict__ Wb) {
  int i = (blockIdx.x * 256 + threadIdx.x) * 8;
  float4 a = *reinterpret_cast<const float4*>(W + i);
  float4 b = *reinterpret_cast<const float4*>(W + i + 4);
  float f[8] = {a.x, a.y, a.z, a.w, b.x, b.y, b.z, b.w};
  *reinterpret_cast<uint4*>(Wb + i) = pack8bf(f);
}

// ---------------------------------------------------------------------------
// K0b: xe (b, c=512, hw=16384) fp32 -> xeT (b, hw, c) bf16  (K-contiguous for MFMA)
__global__ __launch_bounds__(256) void transpose_cvt(const float* __restrict__ x,
                                                     u16* __restrict__ xT) {
  __shared__ float tile[32][33];
  int b = blockIdx.z;
  int c0 = blockIdx.y * 32;     // 16 tiles
  int n0 = blockIdx.x * 32;     // 512 tiles
  int tx = threadIdx.x & 31, ty = threadIdx.x >> 5;
  const float* src = x + ((size_t)b * NC + c0) * NHW + n0;
  for (int k = 0; k < 4; k++)
    tile[ty + k * 8][tx] = src[(size_t)(ty + k * 8) * NHW + tx];
  __syncthreads();
  u16* dst = xT + ((size_t)b * NHW + n0) * NC + c0;
  for (int k = 0; k < 4; k++) {
    int n = ty + k * 8;
    dst[(size_t)n * NC + tx] = f2b(tile[tx][n]);
  }
}

// ---------------------------------------------------------------------------
// K1: 64-channel projection (q or k), output TRANSPOSED bf16: yT[b, hw, o(64)]
// (K-contiguous over o? no: over c for energy -> energy contracts over the 64
//  output channels, so yT rows hw with 64 contiguous channel entries.)
// grid (hw_tiles=128, b=4), block 256.
__global__ __launch_bounds__(256) void proj64T(const float* __restrict__ x,
                                               const float* __restrict__ Wt,
                                               const float* __restrict__ bias,
                                               u16* __restrict__ yT) {
  int b = blockIdx.y;
  int hw0 = blockIdx.x * 128;
  __shared__ float xs[32][128];   // [cc][w]
  __shared__ float ws[64][32];    // [o][cc]
  int t = threadIdx.x;
  int og = t >> 5;      // 0..7  (8 o per group)
  int wl = t & 31;      // 0..31 (4 hw each)
  float acc[8][4];
  for (int i = 0; i < 8; i++) for (int j = 0; j < 4; j++) acc[i][j] = 0.f;
  const float* xb = x + (size_t)b * NC * NHW + hw0;
  for (int c0 = 0; c0 < NC; c0 += 32) {
    for (int i = 0; i < 4; i++) {
      int idx4 = t + i * 256;
      int cc = idx4 >> 5, w4 = (idx4 & 31) * 4;
      float4 v = *reinterpret_cast<const float4*>(&xb[(size_t)(c0 + cc) * NHW + w4]);
      xs[cc][w4 + 0] = v.x; xs[cc][w4 + 1] = v.y; xs[cc][w4 + 2] = v.z; xs[cc][w4 + 3] = v.w;
    }
    for (int i = 0; i < 2; i++) {
      int idx4 = t + i * 256;
      int o = idx4 >> 3, cb4 = (idx4 & 7) * 4;
      float4 v = *reinterpret_cast<const float4*>(&Wt[(size_t)o * NC + c0 + cb4]);
      ws[o][cb4 + 0] = v.x; ws[o][cb4 + 1] = v.y; ws[o][cb4 + 2] = v.z; ws[o][cb4 + 3] = v.w;
    }
    __syncthreads();
    for (int cc = 0; cc < 32; cc++) {
      float a[8], bb[4];
      for (int i = 0; i < 8; i++) a[i] = ws[og * 8 + i][cc];
      for (int j = 0; j < 4; j++) bb[j] = xs[cc][wl * 4 + j];
      for (int i = 0; i < 8; i++)
        for (int j = 0; j < 4; j++) acc[i][j] += a[i] * bb[j];
    }
    __syncthreads();
  }
  float bv[8];
  for (int i = 0; i < 8; i++) bv[i] = bias[og * 8 + i];
  for (int j = 0; j < 4; j++) {
    float col[8];
    for (int i = 0; i < 8; i++) col[i] = acc[i][j] + bv[i];
    size_t hw = (size_t)hw0 + wl * 4 + j;
    *reinterpret_cast<uint4*>(&yT[((size_t)b * NHW + hw) * 64 + og * 8]) = pack8bf(col);
  }
}

// ---------------------------------------------------------------------------
// K2: 512-channel projection (v) via MFMA bf16.  (unchanged from prev round)
__global__ __launch_bounds__(256) void proj_v_mfma(const u16* __restrict__ xT,
                                                   const u16* __restrict__ Wb,
                                                   const float* __restrict__ bias,
                                                   u16* __restrict__ y) {
  __shared__ __align__(16) u16 smem[16384];        // As [0:8192) | Bs [8192:16384)
  char* AsB = (char*)smem;
  char* BsB = (char*)(smem + 8192);
  int o0 = blockIdx.x * 128, n0 = blockIdx.y * 128, b = blockIdx.z;
  int t = threadIdx.x;
  int wid = t >> 6, lane = t & 63;
  int wm = wid >> 1, wn = wid & 1;
  int l15 = lane & 15, lhi = lane >> 4;

  f32x4 acc[4][4];
#pragma unroll
  for (int m = 0; m < 4; m++)
#pragma unroll
    for (int n = 0; n < 4; n++)
#pragma unroll
      for (int r = 0; r < 4; r++) acc[m][n][r] = 0.f;

  const u16* Arow = Wb + (size_t)o0 * NC;
  const u16* Brow = xT + ((size_t)b * NHW + n0) * NC;

  for (int c0 = 0; c0 < NC; c0 += 64) {
#pragma unroll
    for (int p = 0; p < 4; p++) {
      int idx = t + p * 256;            // 0..1023
      int row = idx >> 3;               // 0..127
      int cb  = (idx & 7) * 8;          // elem offset in K
      int dst = row * 128 + ((cb * 2) ^ ((row & 7) << 4));
      bf16x8 av = *reinterpret_cast<const bf16x8*>(Arow + (size_t)row * NC + c0 + cb);
      *reinterpret_cast<bf16x8*>(AsB + dst) = av;
      bf16x8 bv = *reinterpret_cast<const bf16x8*>(Brow + (size_t)row * NC + c0 + cb);
      *reinterpret_cast<bf16x8*>(BsB + dst) = bv;
    }
    __syncthreads();
#pragma unroll
    for (int kk = 0; kk < 2; kk++) {
      int kbyte = kk * 64 + lhi * 16;
      bf16x8 af[4], bfr[4];
#pragma unroll
      for (int m = 0; m < 4; m++) {
        int row = wm * 64 + m * 16 + l15;
        af[m] = *reinterpret_cast<const bf16x8*>(AsB + row * 128 + (kbyte ^ ((row & 7) << 4)));
      }
#pragma unroll
      for (int n = 0; n < 4; n++) {
        int row = wn * 64 + n * 16 + l15;
        bfr[n] = *reinterpret_cast<const bf16x8*>(BsB + row * 128 + (kbyte ^ ((row & 7) << 4)));
      }
#pragma unroll
      for (int m = 0; m < 4; m++)
#pragma unroll
        for (int n = 0; n < 4; n++)
          acc[m][n] = __builtin_amdgcn_mfma_f32_16x16x32_bf16(af[m], bfr[n], acc[m][n], 0, 0, 0);
    }
    __syncthreads();
  }

  char* stage = (char*)smem + wid * 8192;
#pragma unroll
  for (int m = 0; m < 4; m++) {
#pragma unroll
    for (int r = 0; r < 4; r++) {
      int lrow = m * 16 + lhi * 4 + r;
      float bval = bias[o0 + wm * 64 + lrow];
#pragma unroll
      for (int n = 0; n < 4; n++) {
        int col = n * 16 + l15;
        *reinterpret_cast<u16*>(stage + lrow * 128 + col * 2) = f2b(acc[m][n][r] + bval);
      }
    }
  }
  __syncthreads();
#pragma unroll
  for (int s = 0; s < 8; s++) {
    int row  = s * 8 + (lane >> 3);
    int colb = (lane & 7) * 8;
    uint4 v = *reinterpret_cast<const uint4*>(stage + row * 128 + colb * 2);
    size_t addr = ((size_t)b * NC + o0 + wm * 64 + row) * (size_t)NHW + n0 + wn * 64 + colb;
    *reinterpret_cast<uint4*>(&y[addr]) = v;
  }
}

// ---------------------------------------------------------------------------
// K3: transpose last two dims of (planes,128,128) bf16 tensor (v only now)
__global__ __launch_bounds__(256) void transpose128(const u16* __restrict__ src,
                                                    u16* __restrict__ dst) {
  __shared__ u16 tile[32][33];
  int p = blockIdx.z;
  int i0 = blockIdx.y * 32, j0 = blockIdx.x * 32;
  int tx = threadIdx.x & 31, ty = threadIdx.x >> 5;
  const u16* s = src + (size_t)p * NHW;
  u16* d = dst + (size_t)p * NHW;
  for (int k = 0; k < 4; k++) {
    int i = i0 + ty + k * 8;
    tile[ty + k * 8][tx] = s[(size_t)i * 128 + j0 + tx];
  }
  __syncthreads();
  for (int k = 0; k < 4; k++) {
    int j = j0 + ty + k * 8;
    d[(size_t)j * 128 + i0 + tx] = tile[tx][ty + k * 8];
  }
}

// ---------------------------------------------------------------------------
// K4: energy via MFMA. e[r][j] = sum_c A[r][c] * B[j][c], c = 64 channels.
//   isH=0 (energy_W), block s=h: A row r=w -> qT[b, s*128+r, :], B row j -> kT[b, s*128+j, :]
//       store att[b, s, r, 128+j]
//   isH=1 (energy_H), block s=w: A row r=h -> qT[b, r*128+s, :], B row j -> kT[b, j*128+s, :]
//       store att[b, r, s, j], mask j==r with -1e30
__global__ __launch_bounds__(256) void energy_mfma(const u16* __restrict__ QT,
                                                   const u16* __restrict__ KT,
                                                   u16* __restrict__ att, int isH) {
  __shared__ __align__(16) u16 smem[16384];        // As 16KB | Bs 16KB (rows 128 x 64 bf16)
  char* AsB = (char*)smem;
  char* BsB = (char*)(smem + 8192);
  int s = blockIdx.x, b = blockIdx.y;
  int t = threadIdx.x;
  int wid = t >> 6, lane = t & 63;
  int wm = wid >> 1, wn = wid & 1;
  int l15 = lane & 15, lhi = lane >> 4;

  size_t base = (size_t)b * NHW * 64;
  size_t rowstride = isH ? (size_t)128 * 64 : 64;
  size_t off0 = isH ? (size_t)s * 64 : (size_t)s * 128 * 64;

  f32x4 acc[4][4];
#pragma unroll
  for (int m = 0; m < 4; m++)
#pragma unroll
    for (int n = 0; n < 4; n++)
#pragma unroll
      for (int r = 0; r < 4; r++) acc[m][n][r] = 0.f;

#pragma unroll
  for (int p = 0; p < 4; p++) {
    int idx = t + p * 256;              // 0..1023
    int row = idx >> 3;                 // 0..127
    int cb  = (idx & 7) * 8;            // 0..56
    int dst = row * 128 + ((cb * 2) ^ ((row & 7) << 4));
    bf16x8 av = *reinterpret_cast<const bf16x8*>(QT + base + off0 + (size_t)row * rowstride + cb);
    *reinterpret_cast<bf16x8*>(AsB + dst) = av;
    bf16x8 bv = *reinterpret_cast<const bf16x8*>(KT + base + off0 + (size_t)row * rowstride + cb);
    *reinterpret_cast<bf16x8*>(BsB + dst) = bv;
  }
  __syncthreads();
#pragma unroll
  for (int kk = 0; kk < 2; kk++) {
    int kbyte = kk * 64 + lhi * 16;
    bf16x8 af[4], bfr[4];
#pragma unroll
    for (int m = 0; m < 4; m++) {
      int row = wm * 64 + m * 16 + l15;
      af[m] = *reinterpret_cast<const bf16x8*>(AsB + row * 128 + (kbyte ^ ((row & 7) << 4)));
    }
#pragma unroll
    for (int n = 0; n < 4; n++) {
      int row = wn * 64 + n * 16 + l15;
      bfr[n] = *reinterpret_cast<const bf16x8*>(BsB + row * 128 + (kbyte ^ ((row & 7) << 4)));
    }
#pragma unroll
    for (int m = 0; m < 4; m++)
#pragma unroll
      for (int n = 0; n < 4; n++)
        acc[m][n] = __builtin_amdgcn_mfma_f32_16x16x32_bf16(af[m], bfr[n], acc[m][n], 0, 0, 0);
  }
  __syncthreads();   // protect As/Bs until all waves done reading

  // repack to bf16 via per-wave LDS stage (64x64), apply diag mask for isH
  char* stage = (char*)smem + wid * 8192;
#pragma unroll
  for (int m = 0; m < 4; m++) {
#pragma unroll
    for (int r = 0; r < 4; r++) {
      int lrow = m * 16 + lhi * 4 + r;              // local r
      int grow = wm * 64 + lrow;                    // global r
#pragma unroll
      for (int n = 0; n < 4; n++) {
        int col = n * 16 + l15;                     // local j
        int gcol = wn * 64 + col;                   // global j
        float v = acc[m][n][r];
        if (isH && gcol == grow) v = -1e30f;
        *reinterpret_cast<u16*>(stage + lrow * 128 + col * 2) = f2b(v);
      }
    }
  }
  __syncthreads();
  size_t attb = (size_t)b * 4194304;
#pragma unroll
  for (int sb = 0; sb < 8; sb++) {
    int row  = wm * 64 + sb * 8 + (lane >> 3);      // global r
    int colb = wn * 64 + (lane & 7) * 8;            // global j base
    uint4 v = *reinterpret_cast<const uint4*>(stage + (sb * 8 + (lane >> 3)) * 128 + (lane & 7) * 16);
    size_t addr = attb + (isH ? ((size_t)row * 32768 + (size_t)s * 256 + colb)
                              : ((size_t)s * 32768 + (size_t)row * 256 + 128 + colb));
    *reinterpret_cast<uint4*>(&att[addr]) = v;
  }
}

// ---------------------------------------------------------------------------
// K5: softmax over 256-entry rows, in place. One wave per row.
__global__ __launch_bounds__(256) void softmax_kern(u16* __restrict__ att) {
  int wave = threadIdx.x >> 6;
  int lane = threadIdx.x & 63;
  size_t row = (size_t)blockIdx.x * 4 + wave;
  u16* p = att + row * 256;
  uint2 u = *reinterpret_cast<const uint2*>(&p[lane * 4]);
  float v[4];
  v[0] = b2f((u16)(u.x & 0xFFFF)); v[1] = b2f((u16)(u.x >> 16));
  v[2] = b2f((u16)(u.y & 0xFFFF)); v[3] = b2f((u16)(u.y >> 16));
  float mx = fmaxf(fmaxf(v[0], v[1]), fmaxf(v[2], v[3]));
  for (int off = 32; off; off >>= 1) mx = fmaxf(mx, __shfl_xor(mx, off));
  float sum = 0.f;
  for (int i = 0; i < 4; i++) { v[i] = __expf(v[i] - mx); sum += v[i]; }
  for (int off = 32; off; off >>= 1) sum += __shfl_xor(sum, off);
  float inv = 1.f / sum;
  uint2 o;
  o.x = (uint32_t)f2b(v[0] * inv) | ((uint32_t)f2b(v[1] * inv) << 16);
  o.y = (uint32_t)f2b(v[2] * inv) | ((uint32_t)f2b(v[3] * inv) << 16);
  *reinterpret_cast<uint2*>(&p[lane * 4]) = o;
}

// ---------------------------------------------------------------------------
// K6: output GEMM via MFMA, IN-PLACE over V (bf16 out).
//   out[c][r] = sum_j V[b, ct*128+c, s*128+j] * Batt[r][j],  M=c(128) N=r(128) K=j(128)
//   isH=0: Batt row r = att[b, s, r, 128+j]  (stride 256)
//   isH=1: Batt row r = att[b, r, s, j]      (stride 32768)
//   out addr = (b*512 + ct*128 + c)*16384 + s*128 + r  == V's own tile (safe in-place:
//   each block reads exactly its own output tile before the post-barrier stores).
__global__ __launch_bounds__(256) void out_gemm_mfma(const u16* __restrict__ V,
                                                     const u16* __restrict__ att,
                                                     u16* __restrict__ out, int isH) {
  __shared__ __align__(16) u16 smem[16384];
  char* AsB = (char*)smem;
  char* BsB = (char*)(smem + 8192);
  int ct = blockIdx.x, s = blockIdx.y, b = blockIdx.z;
  int t = threadIdx.x;
  int wid = t >> 6, lane = t & 63;
  int wm = wid >> 1, wn = wid & 1;
  int l15 = lane & 15, lhi = lane >> 4;

  f32x4 acc[4][4];
#pragma unroll
  for (int m = 0; m < 4; m++)
#pragma unroll
    for (int n = 0; n < 4; n++)
#pragma unroll
      for (int r = 0; r < 4; r++) acc[m][n][r] = 0.f;

  const u16* Abase = V + ((size_t)(b * NC + ct * 128)) * NHW + (size_t)s * 128;
  size_t attb = (size_t)b * 4194304;
  size_t bbase = attb + (isH ? (size_t)s * 256 : (size_t)s * 32768 + 128);
  size_t bstride = isH ? 32768 : 256;

  for (int c0 = 0; c0 < 128; c0 += 64) {
#pragma unroll
    for (int p = 0; p < 4; p++) {
      int idx = t + p * 256;
      int row = idx >> 3;
      int cb  = (idx & 7) * 8;
      int dst = row * 128 + ((cb * 2) ^ ((row & 7) << 4));
      bf16x8 av = *reinterpret_cast<const bf16x8*>(Abase + (size_t)row * NHW + c0 + cb);
      *reinterpret_cast<bf16x8*>(AsB + dst) = av;
      bf16x8 bv = *reinterpret_cast<const bf16x8*>(att + bbase + (size_t)row * bstride + c0 + cb);
      *reinterpret_cast<bf16x8*>(BsB + dst) = bv;
    }
    __syncthreads();
#pragma unroll
    for (int kk = 0; kk < 2; kk++) {
      int kbyte = kk * 64 + lhi * 16;
      bf16x8 af[4], bfr[4];
#pragma unroll
      for (int m = 0; m < 4; m++) {
        int row = wm * 64 + m * 16 + l15;
        af[m] = *reinterpret_cast<const bf16x8*>(AsB + row * 128 + (kbyte ^ ((row & 7) << 4)));
      }
#pragma unroll
      for (int n = 0; n < 4; n++) {
        int row = wn * 64 + n * 16 + l15;
        bfr[n] = *reinterpret_cast<const bf16x8*>(BsB + row * 128 + (kbyte ^ ((row & 7) << 4)));
      }
#pragma unroll
      for (int m = 0; m < 4; m++)
#pragma unroll
        for (int n = 0; n < 4; n++)
          acc[m][n] = __builtin_amdgcn_mfma_f32_16x16x32_bf16(af[m], bfr[n], acc[m][n], 0, 0, 0);
    }
    __syncthreads();
  }

  char* stage = (char*)smem + wid * 8192;
#pragma unroll
  for (int m = 0; m < 4; m++) {
#pragma unroll
    for (int r = 0; r < 4; r++) {
      int lrow = m * 16 + lhi * 4 + r;              // local c
#pragma unroll
      for (int n = 0; n < 4; n++) {
        int col = n * 16 + l15;                     // local r
        *reinterpret_cast<u16*>(stage + lrow * 128 + col * 2) = f2b(acc[m][n][r]);
      }
    }
  }
  __syncthreads();
#pragma unroll
  for (int sb = 0; sb < 8; sb++) {
    int row  = sb * 8 + (lane >> 3);
    int colb = (lane & 7) * 8;
    uint4 v = *reinterpret_cast<const uint4*>(stage + row * 128 + colb * 2);
    size_t addr = ((size_t)(b * NC + ct * 128 + wm * 64 + row)) * NHW + (size_t)s * 128 + wn * 64 + colb;
    *reinterpret_cast<uint4*>(&out[addr]) = v;
  }
}

// ---------------------------------------------------------------------------
// K7: epilogue. out0 = g1*(outW + outH^T + 2) + xe ; out1 = g2*(...) + xq
// outW now bf16 (b,c,h,w); outHsw bf16 (b,c,w,h) transposed through LDS.
__global__ __launch_bounds__(256) void epilogue(const u16* __restrict__ outWbf,
                                                const u16* __restrict__ outHsw,
                                                const float* __restrict__ xe,
                                                const float* __restrict__ xq,
                                                const float* __restrict__ g1p,
                                                const float* __restrict__ g2p,
                                                float* out0, float* out1) {
  __shared__ float tile[32][33];
  int p = blockIdx.z;                 // b*512 + c
  int h0 = blockIdx.y * 32, w0 = blockIdx.x * 32;
  int tx = threadIdx.x & 31, ty = threadIdx.x >> 5;
  const u16* src = outHsw + (size_t)p * NHW;   // [w][h]
  for (int k = 0; k < 4; k++) {
    int w = w0 + ty + k * 8;
    tile[ty + k * 8][tx] = b2f(src[(size_t)w * 128 + h0 + tx]);
  }
  __syncthreads();
  float g1 = g1p[0], g2 = g2p[0];
  for (int k = 0; k < 4; k++) {
    int h = h0 + ty + k * 8;
    size_t idx = (size_t)p * NHW + (size_t)h * 128 + w0 + tx;
    float sum = b2f(outWbf[idx]) + tile[tx][ty + k * 8] + 2.0f;
    out0[idx] = g1 * sum + xe[idx];
    out1[idx] = g2 * sum + xq[idx];
  }
}

// ---------------------------------------------------------------------------
extern "C" void kernel_launch(void* const* d_in, const int* in_sizes, int n_in,
                              void* d_out, int out_size, void* d_ws, size_t ws_size,
                              hipStream_t stream) {
  (void)in_sizes; (void)n_in; (void)out_size; (void)ws_size;
  const float* xe = (const float*)d_in[0];
  const float* xq = (const float*)d_in[1];
  const float* Wq = (const float*)d_in[2];
  const float* bq = (const float*)d_in[3];
  const float* Wk = (const float*)d_in[4];
  const float* bk = (const float*)d_in[5];
  const float* Wv = (const float*)d_in[6];
  const float* bv = (const float*)d_in[7];
  const float* g1 = (const float*)d_in[8];
  const float* g2 = (const float*)d_in[9];
  float* out = (float*)d_out;

  char* ws = (char*)d_ws;
  u16* qT    = (u16*)(ws + 0);            //  8 MiB  (4,16384,64) bf16
  u16* kT    = (u16*)(ws + 8388608);      //  8 MiB
  u16* wv_bf = (u16*)(ws + 16777216);     //  0.5 MiB
  u16* v_n   = (u16*)(ws + 33554432);     // 64 MiB  (4,512,128,128) -> becomes outW bf16
  u16* v_sw  = (u16*)(ws + 100663296);    // 64 MiB  (b,c,w,h)       -> becomes outHsw bf16
  u16* att   = (u16*)(ws + 167772160);    // 32 MiB  (4,128,128,256)
  u16* xeT   = (u16*)(ws + 201326592);    // 64 MiB  (b,hw,c) bf16

  convert_w<<<dim3(128), 256, 0, stream>>>(Wv, wv_bf);
  transpose_cvt<<<dim3(512, 16, 4), 256, 0, stream>>>(xe, xeT);
  proj64T<<<dim3(128, 4), 256, 0, stream>>>(xq, Wq, bq, qT);
  proj64T<<<dim3(128, 4), 256, 0, stream>>>(xe, Wk, bk, kT);
  proj_v_mfma<<<dim3(4, 128, 4), 256, 0, stream>>>(xeT, wv_bf, bv, v_n);
  transpose128<<<dim3(4, 4, 2048), 256, 0, stream>>>(v_n, v_sw);
  energy_mfma<<<dim3(128, 4), 256, 0, stream>>>(qT, kT, att, 0);
  energy_mfma<<<dim3(128, 4), 256, 0, stream>>>(qT, kT, att, 1);
  softmax_kern<<<dim3(16384), 256, 0, stream>>>(att);
  out_gemm_mfma<<<dim3(4, 128, 4), 256, 0, stream>>>(v_n, att, v_n, 0);   // in-place
  out_gemm_mfma<<<dim3(4, 128, 4), 256, 0, stream>>>(v_sw, att, v_sw, 1); // in-place
  epilogue<<<dim3(4, 4, 2048), 256, 0, stream>>>(v_n, v_sw, xe, xq, g1, g2,
                                                 out, out + 33554432);
}

// Round 3
// 770.962 us; speedup vs baseline: 1.8267x; 1.1202x over previous
//
#include <hip/hip_runtime.h>
#include <stdint.h>

typedef unsigned short u16;   // raw bf16 bits
typedef __attribute__((ext_vector_type(8))) short bf16x8;
typedef __attribute__((ext_vector_type(4))) float f32x4;

#define NB   4
#define NC   512
#define NC8  64
#define NH   128
#define NW   128
#define NHW  16384

__device__ __forceinline__ float b2f(u16 u) {
  union { float f; uint32_t i; } x; x.i = ((uint32_t)u) << 16; return x.f;
}
__device__ __forceinline__ u16 f2b(float f) {
  union { float f; uint32_t u; } x; x.f = f;
  uint32_t r = x.u + 0x7FFF + ((x.u >> 16) & 1);
  return (u16)(r >> 16);
}
__device__ __forceinline__ uint4 pack8bf(const float* f) {
  uint4 u;
  u.x = (uint32_t)f2b(f[0]) | ((uint32_t)f2b(f[1]) << 16);
  u.y = (uint32_t)f2b(f[2]) | ((uint32_t)f2b(f[3]) << 16);
  u.z = (uint32_t)f2b(f[4]) | ((uint32_t)f2b(f[5]) << 16);
  u.w = (uint32_t)f2b(f[6]) | ((uint32_t)f2b(f[7]) << 16);
  return u;
}
__device__ __forceinline__ void unpack8bf(uint4 u, float* f) {
  f[0] = b2f((u16)(u.x & 0xFFFF)); f[1] = b2f((u16)(u.x >> 16));
  f[2] = b2f((u16)(u.y & 0xFFFF)); f[3] = b2f((u16)(u.y >> 16));
  f[4] = b2f((u16)(u.z & 0xFFFF)); f[5] = b2f((u16)(u.z >> 16));
  f[6] = b2f((u16)(u.w & 0xFFFF)); f[7] = b2f((u16)(u.w >> 16));
}

// ---------------------------------------------------------------------------
// K0a: convert fp32 weight matrix -> bf16, same layout. grid = elems/2048.
__global__ __launch_bounds__(256) void convert_w(const float* __restrict__ W,
                                                 u16* __restrict__ Wb) {
  int i = (blockIdx.x * 256 + threadIdx.x) * 8;
  float4 a = *reinterpret_cast<const float4*>(W + i);
  float4 b = *reinterpret_cast<const float4*>(W + i + 4);
  float f[8] = {a.x, a.y, a.z, a.w, b.x, b.y, b.z, b.w};
  *reinterpret_cast<uint4*>(Wb + i) = pack8bf(f);
}

// ---------------------------------------------------------------------------
// K0b: x (b, c=512, hw=16384) fp32 -> xT (b, hw, c) bf16  (K-contiguous for MFMA)
// Vectorized write phase: 8 c per thread as uint4.
__global__ __launch_bounds__(256) void transpose_cvt(const float* __restrict__ x,
                                                     u16* __restrict__ xT) {
  __shared__ float tile[32][33];   // [cc][n]
  int b = blockIdx.z;
  int c0 = blockIdx.y * 32;
  int n0 = blockIdx.x * 32;
  int t = threadIdx.x;
  int tx = t & 31, ty = t >> 5;
  const float* src = x + ((size_t)b * NC + c0) * NHW + n0;
  for (int k = 0; k < 4; k++)
    tile[ty + k * 8][tx] = src[(size_t)(ty + k * 8) * NHW + tx];
  __syncthreads();
  if (t < 128) {
    int n = t >> 2, cg = t & 3;
    float f[8];
    for (int j = 0; j < 8; j++) f[j] = tile[cg * 8 + j][n];
    *reinterpret_cast<uint4*>(&xT[((size_t)b * NHW + n0 + n) * NC + c0 + cg * 8]) = pack8bf(f);
  }
}

// ---------------------------------------------------------------------------
// K1: 64-channel projection via MFMA: yT[b, hw, o(64)] = sum_c Wb[o,c] xT[b,hw,c] + bias
//   M=64, N tile=128 (hw), BK=64. 4 waves 2x2: wave tile 32(M) x 64(N).
// grid (hw_tiles=128, b=4), block 256.
__global__ __launch_bounds__(256) void proj64_mfma(const u16* __restrict__ xT,
                                                   const u16* __restrict__ Wb,
                                                   const float* __restrict__ bias,
                                                   u16* __restrict__ yT) {
  __shared__ __align__(16) u16 smem[12288];   // As 8KB | Bs 16KB ; out stage reuses 16KB
  char* AsB = (char*)smem;
  char* BsB = (char*)smem + 8192;
  int n0 = blockIdx.x * 128, b = blockIdx.y;
  int t = threadIdx.x;
  int wid = t >> 6, lane = t & 63;
  int wm = wid >> 1, wn = wid & 1;
  int l15 = lane & 15, lhi = lane >> 4;

  f32x4 acc[2][4];
#pragma unroll
  for (int m = 0; m < 2; m++)
#pragma unroll
    for (int n = 0; n < 4; n++)
#pragma unroll
      for (int r = 0; r < 4; r++) acc[m][n][r] = 0.f;

  const u16* Bbase = xT + ((size_t)b * NHW + n0) * NC;

  for (int c0 = 0; c0 < NC; c0 += 64) {
#pragma unroll
    for (int p = 0; p < 2; p++) {          // A: 64 rows x 64 K
      int idx = t + p * 256;               // 0..511
      int row = idx >> 3, cb = (idx & 7) * 8;
      int dst = row * 128 + ((cb * 2) ^ ((row & 7) << 4));
      bf16x8 av = *reinterpret_cast<const bf16x8*>(Wb + (size_t)row * NC + c0 + cb);
      *reinterpret_cast<bf16x8*>(AsB + dst) = av;
    }
#pragma unroll
    for (int p = 0; p < 4; p++) {          // B: 128 rows x 64 K
      int idx = t + p * 256;               // 0..1023
      int row = idx >> 3, cb = (idx & 7) * 8;
      int dst = row * 128 + ((cb * 2) ^ ((row & 7) << 4));
      bf16x8 bv = *reinterpret_cast<const bf16x8*>(Bbase + (size_t)row * NC + c0 + cb);
      *reinterpret_cast<bf16x8*>(BsB + dst) = bv;
    }
    __syncthreads();
#pragma unroll
    for (int kk = 0; kk < 2; kk++) {
      int kbyte = kk * 64 + lhi * 16;
      bf16x8 af[2], bfr[4];
#pragma unroll
      for (int m = 0; m < 2; m++) {
        int row = wm * 32 + m * 16 + l15;
        af[m] = *reinterpret_cast<const bf16x8*>(AsB + row * 128 + (kbyte ^ ((row & 7) << 4)));
      }
#pragma unroll
      for (int n = 0; n < 4; n++) {
        int row = wn * 64 + n * 16 + l15;
        bfr[n] = *reinterpret_cast<const bf16x8*>(BsB + row * 128 + (kbyte ^ ((row & 7) << 4)));
      }
#pragma unroll
      for (int m = 0; m < 2; m++)
#pragma unroll
        for (int n = 0; n < 4; n++)
          acc[m][n] = __builtin_amdgcn_mfma_f32_16x16x32_bf16(af[m], bfr[n], acc[m][n], 0, 0, 0);
    }
    __syncthreads();
  }

  // stage [col(hw) 128][o 64] bf16 (swizzled), then coalesced 16B stores
  char* stage = (char*)smem;
#pragma unroll
  for (int m = 0; m < 2; m++) {
#pragma unroll
    for (int r = 0; r < 4; r++) {
      int o = wm * 32 + m * 16 + lhi * 4 + r;
      float bval = bias[o];
#pragma unroll
      for (int n = 0; n < 4; n++) {
        int col = wn * 64 + n * 16 + l15;
        int byte = col * 128 + ((o * 2) ^ ((col & 7) << 4));
        *reinterpret_cast<u16*>(stage + byte) = f2b(acc[m][n][r] + bval);
      }
    }
  }
  __syncthreads();
#pragma unroll
  for (int p = 0; p < 4; p++) {
    int idx = t + p * 256;                 // 0..1023 = 128 cols x 8 segs
    int col = idx >> 3, seg = idx & 7;
    int byte = col * 128 + ((seg * 16) ^ ((col & 7) << 4));
    uint4 v = *reinterpret_cast<const uint4*>(stage + byte);
    *reinterpret_cast<uint4*>(&yT[((size_t)b * NHW + n0 + col) * 64 + seg * 8]) = v;
  }
}

// ---------------------------------------------------------------------------
// K2: 512-channel projection (v) via MFMA bf16.  (unchanged, proven)
__global__ __launch_bounds__(256) void proj_v_mfma(const u16* __restrict__ xT,
                                                   const u16* __restrict__ Wb,
                                                   const float* __restrict__ bias,
                                                   u16* __restrict__ y) {
  __shared__ __align__(16) u16 smem[16384];
  char* AsB = (char*)smem;
  char* BsB = (char*)(smem + 8192);
  int o0 = blockIdx.x * 128, n0 = blockIdx.y * 128, b = blockIdx.z;
  int t = threadIdx.x;
  int wid = t >> 6, lane = t & 63;
  int wm = wid >> 1, wn = wid & 1;
  int l15 = lane & 15, lhi = lane >> 4;

  f32x4 acc[4][4];
#pragma unroll
  for (int m = 0; m < 4; m++)
#pragma unroll
    for (int n = 0; n < 4; n++)
#pragma unroll
      for (int r = 0; r < 4; r++) acc[m][n][r] = 0.f;

  const u16* Arow = Wb + (size_t)o0 * NC;
  const u16* Brow = xT + ((size_t)b * NHW + n0) * NC;

  for (int c0 = 0; c0 < NC; c0 += 64) {
#pragma unroll
    for (int p = 0; p < 4; p++) {
      int idx = t + p * 256;
      int row = idx >> 3;
      int cb  = (idx & 7) * 8;
      int dst = row * 128 + ((cb * 2) ^ ((row & 7) << 4));
      bf16x8 av = *reinterpret_cast<const bf16x8*>(Arow + (size_t)row * NC + c0 + cb);
      *reinterpret_cast<bf16x8*>(AsB + dst) = av;
      bf16x8 bv = *reinterpret_cast<const bf16x8*>(Brow + (size_t)row * NC + c0 + cb);
      *reinterpret_cast<bf16x8*>(BsB + dst) = bv;
    }
    __syncthreads();
#pragma unroll
    for (int kk = 0; kk < 2; kk++) {
      int kbyte = kk * 64 + lhi * 16;
      bf16x8 af[4], bfr[4];
#pragma unroll
      for (int m = 0; m < 4; m++) {
        int row = wm * 64 + m * 16 + l15;
        af[m] = *reinterpret_cast<const bf16x8*>(AsB + row * 128 + (kbyte ^ ((row & 7) << 4)));
      }
#pragma unroll
      for (int n = 0; n < 4; n++) {
        int row = wn * 64 + n * 16 + l15;
        bfr[n] = *reinterpret_cast<const bf16x8*>(BsB + row * 128 + (kbyte ^ ((row & 7) << 4)));
      }
#pragma unroll
      for (int m = 0; m < 4; m++)
#pragma unroll
        for (int n = 0; n < 4; n++)
          acc[m][n] = __builtin_amdgcn_mfma_f32_16x16x32_bf16(af[m], bfr[n], acc[m][n], 0, 0, 0);
    }
    __syncthreads();
  }

  char* stage = (char*)smem + wid * 8192;
#pragma unroll
  for (int m = 0; m < 4; m++) {
#pragma unroll
    for (int r = 0; r < 4; r++) {
      int lrow = m * 16 + lhi * 4 + r;
      float bval = bias[o0 + wm * 64 + lrow];
#pragma unroll
      for (int n = 0; n < 4; n++) {
        int col = n * 16 + l15;
        *reinterpret_cast<u16*>(stage + lrow * 128 + col * 2) = f2b(acc[m][n][r] + bval);
      }
    }
  }
  __syncthreads();
#pragma unroll
  for (int s = 0; s < 8; s++) {
    int row  = s * 8 + (lane >> 3);
    int colb = (lane & 7) * 8;
    uint4 v = *reinterpret_cast<const uint4*>(stage + row * 128 + colb * 2);
    size_t addr = ((size_t)b * NC + o0 + wm * 64 + row) * (size_t)NHW + n0 + wn * 64 + colb;
    *reinterpret_cast<uint4*>(&y[addr]) = v;
  }
}

// ---------------------------------------------------------------------------
// K3: transpose last two dims of (planes,128,128) bf16 tensor (v only)
__global__ __launch_bounds__(256) void transpose128(const u16* __restrict__ src,
                                                    u16* __restrict__ dst) {
  __shared__ u16 tile[32][33];
  int p = blockIdx.z;
  int i0 = blockIdx.y * 32, j0 = blockIdx.x * 32;
  int tx = threadIdx.x & 31, ty = threadIdx.x >> 5;
  const u16* s = src + (size_t)p * NHW;
  u16* d = dst + (size_t)p * NHW;
  for (int k = 0; k < 4; k++) {
    int i = i0 + ty + k * 8;
    tile[ty + k * 8][tx] = s[(size_t)i * 128 + j0 + tx];
  }
  __syncthreads();
  for (int k = 0; k < 4; k++) {
    int j = j0 + ty + k * 8;
    d[(size_t)j * 128 + i0 + tx] = tile[tx][ty + k * 8];
  }
}

// ---------------------------------------------------------------------------
// K4: energy via MFMA (unchanged, proven).
__global__ __launch_bounds__(256) void energy_mfma(const u16* __restrict__ QT,
                                                   const u16* __restrict__ KT,
                                                   u16* __restrict__ att, int isH) {
  __shared__ __align__(16) u16 smem[16384];
  char* AsB = (char*)smem;
  char* BsB = (char*)(smem + 8192);
  int s = blockIdx.x, b = blockIdx.y;
  int t = threadIdx.x;
  int wid = t >> 6, lane = t & 63;
  int wm = wid >> 1, wn = wid & 1;
  int l15 = lane & 15, lhi = lane >> 4;

  size_t base = (size_t)b * NHW * 64;
  size_t rowstride = isH ? (size_t)128 * 64 : 64;
  size_t off0 = isH ? (size_t)s * 64 : (size_t)s * 128 * 64;

  f32x4 acc[4][4];
#pragma unroll
  for (int m = 0; m < 4; m++)
#pragma unroll
    for (int n = 0; n < 4; n++)
#pragma unroll
      for (int r = 0; r < 4; r++) acc[m][n][r] = 0.f;

#pragma unroll
  for (int p = 0; p < 4; p++) {
    int idx = t + p * 256;
    int row = idx >> 3;
    int cb  = (idx & 7) * 8;
    int dst = row * 128 + ((cb * 2) ^ ((row & 7) << 4));
    bf16x8 av = *reinterpret_cast<const bf16x8*>(QT + base + off0 + (size_t)row * rowstride + cb);
    *reinterpret_cast<bf16x8*>(AsB + dst) = av;
    bf16x8 bv = *reinterpret_cast<const bf16x8*>(KT + base + off0 + (size_t)row * rowstride + cb);
    *reinterpret_cast<bf16x8*>(BsB + dst) = bv;
  }
  __syncthreads();
#pragma unroll
  for (int kk = 0; kk < 2; kk++) {
    int kbyte = kk * 64 + lhi * 16;
    bf16x8 af[4], bfr[4];
#pragma unroll
    for (int m = 0; m < 4; m++) {
      int row = wm * 64 + m * 16 + l15;
      af[m] = *reinterpret_cast<const bf16x8*>(AsB + row * 128 + (kbyte ^ ((row & 7) << 4)));
    }
#pragma unroll
    for (int n = 0; n < 4; n++) {
      int row = wn * 64 + n * 16 + l15;
      bfr[n] = *reinterpret_cast<const bf16x8*>(BsB + row * 128 + (kbyte ^ ((row & 7) << 4)));
    }
#pragma unroll
    for (int m = 0; m < 4; m++)
#pragma unroll
      for (int n = 0; n < 4; n++)
        acc[m][n] = __builtin_amdgcn_mfma_f32_16x16x32_bf16(af[m], bfr[n], acc[m][n], 0, 0, 0);
  }
  __syncthreads();

  char* stage = (char*)smem + wid * 8192;
#pragma unroll
  for (int m = 0; m < 4; m++) {
#pragma unroll
    for (int r = 0; r < 4; r++) {
      int lrow = m * 16 + lhi * 4 + r;
      int grow = wm * 64 + lrow;
#pragma unroll
      for (int n = 0; n < 4; n++) {
        int col = n * 16 + l15;
        int gcol = wn * 64 + col;
        float v = acc[m][n][r];
        if (isH && gcol == grow) v = -1e30f;
        *reinterpret_cast<u16*>(stage + lrow * 128 + col * 2) = f2b(v);
      }
    }
  }
  __syncthreads();
  size_t attb = (size_t)b * 4194304;
#pragma unroll
  for (int sb = 0; sb < 8; sb++) {
    int row  = wm * 64 + sb * 8 + (lane >> 3);
    int colb = wn * 64 + (lane & 7) * 8;
    uint4 v = *reinterpret_cast<const uint4*>(stage + (sb * 8 + (lane >> 3)) * 128 + (lane & 7) * 16);
    size_t addr = attb + (isH ? ((size_t)row * 32768 + (size_t)s * 256 + colb)
                              : ((size_t)s * 32768 + (size_t)row * 256 + 128 + colb));
    *reinterpret_cast<uint4*>(&att[addr]) = v;
  }
}

// ---------------------------------------------------------------------------
// K5: softmax over 256-entry rows, in place. One wave per row.
__global__ __launch_bounds__(256) void softmax_kern(u16* __restrict__ att) {
  int wave = threadIdx.x >> 6;
  int lane = threadIdx.x & 63;
  size_t row = (size_t)blockIdx.x * 4 + wave;
  u16* p = att + row * 256;
  uint2 u = *reinterpret_cast<const uint2*>(&p[lane * 4]);
  float v[4];
  v[0] = b2f((u16)(u.x & 0xFFFF)); v[1] = b2f((u16)(u.x >> 16));
  v[2] = b2f((u16)(u.y & 0xFFFF)); v[3] = b2f((u16)(u.y >> 16));
  float mx = fmaxf(fmaxf(v[0], v[1]), fmaxf(v[2], v[3]));
  for (int off = 32; off; off >>= 1) mx = fmaxf(mx, __shfl_xor(mx, off));
  float sum = 0.f;
  for (int i = 0; i < 4; i++) { v[i] = __expf(v[i] - mx); sum += v[i]; }
  for (int off = 32; off; off >>= 1) sum += __shfl_xor(sum, off);
  float inv = 1.f / sum;
  uint2 o;
  o.x = (uint32_t)f2b(v[0] * inv) | ((uint32_t)f2b(v[1] * inv) << 16);
  o.y = (uint32_t)f2b(v[2] * inv) | ((uint32_t)f2b(v[3] * inv) << 16);
  *reinterpret_cast<uint2*>(&p[lane * 4]) = o;
}

// ---------------------------------------------------------------------------
// K6: output GEMM via MFMA, IN-PLACE over V (bf16 out). (unchanged, proven)
__global__ __launch_bounds__(256) void out_gemm_mfma(const u16* __restrict__ V,
                                                     const u16* __restrict__ att,
                                                     u16* __restrict__ out, int isH) {
  __shared__ __align__(16) u16 smem[16384];
  char* AsB = (char*)smem;
  char* BsB = (char*)(smem + 8192);
  int ct = blockIdx.x, s = blockIdx.y, b = blockIdx.z;
  int t = threadIdx.x;
  int wid = t >> 6, lane = t & 63;
  int wm = wid >> 1, wn = wid & 1;
  int l15 = lane & 15, lhi = lane >> 4;

  f32x4 acc[4][4];
#pragma unroll
  for (int m = 0; m < 4; m++)
#pragma unroll
    for (int n = 0; n < 4; n++)
#pragma unroll
      for (int r = 0; r < 4; r++) acc[m][n][r] = 0.f;

  const u16* Abase = V + ((size_t)(b * NC + ct * 128)) * NHW + (size_t)s * 128;
  size_t attb = (size_t)b * 4194304;
  size_t bbase = attb + (isH ? (size_t)s * 256 : (size_t)s * 32768 + 128);
  size_t bstride = isH ? 32768 : 256;

  for (int c0 = 0; c0 < 128; c0 += 64) {
#pragma unroll
    for (int p = 0; p < 4; p++) {
      int idx = t + p * 256;
      int row = idx >> 3;
      int cb  = (idx & 7) * 8;
      int dst = row * 128 + ((cb * 2) ^ ((row & 7) << 4));
      bf16x8 av = *reinterpret_cast<const bf16x8*>(Abase + (size_t)row * NHW + c0 + cb);
      *reinterpret_cast<bf16x8*>(AsB + dst) = av;
      bf16x8 bv = *reinterpret_cast<const bf16x8*>(att + bbase + (size_t)row * bstride + c0 + cb);
      *reinterpret_cast<bf16x8*>(BsB + dst) = bv;
    }
    __syncthreads();
#pragma unroll
    for (int kk = 0; kk < 2; kk++) {
      int kbyte = kk * 64 + lhi * 16;
      bf16x8 af[4], bfr[4];
#pragma unroll
      for (int m = 0; m < 4; m++) {
        int row = wm * 64 + m * 16 + l15;
        af[m] = *reinterpret_cast<const bf16x8*>(AsB + row * 128 + (kbyte ^ ((row & 7) << 4)));
      }
#pragma unroll
      for (int n = 0; n < 4; n++) {
        int row = wn * 64 + n * 16 + l15;
        bfr[n] = *reinterpret_cast<const bf16x8*>(BsB + row * 128 + (kbyte ^ ((row & 7) << 4)));
      }
#pragma unroll
      for (int m = 0; m < 4; m++)
#pragma unroll
        for (int n = 0; n < 4; n++)
          acc[m][n] = __builtin_amdgcn_mfma_f32_16x16x32_bf16(af[m], bfr[n], acc[m][n], 0, 0, 0);
    }
    __syncthreads();
  }

  char* stage = (char*)smem + wid * 8192;
#pragma unroll
  for (int m = 0; m < 4; m++) {
#pragma unroll
    for (int r = 0; r < 4; r++) {
      int lrow = m * 16 + lhi * 4 + r;
#pragma unroll
      for (int n = 0; n < 4; n++) {
        int col = n * 16 + l15;
        *reinterpret_cast<u16*>(stage + lrow * 128 + col * 2) = f2b(acc[m][n][r]);
      }
    }
  }
  __syncthreads();
#pragma unroll
  for (int sb = 0; sb < 8; sb++) {
    int row  = sb * 8 + (lane >> 3);
    int colb = (lane & 7) * 8;
    uint4 v = *reinterpret_cast<const uint4*>(stage + row * 128 + colb * 2);
    size_t addr = ((size_t)(b * NC + ct * 128 + wm * 64 + row)) * NHW + (size_t)s * 128 + wn * 64 + colb;
    *reinterpret_cast<uint4*>(&out[addr]) = v;
  }
}

// ---------------------------------------------------------------------------
// K7: epilogue, fully vectorized. out0 = g1*(outW + outH^T + 2) + xe ; out1 = g2*(..) + xq
// Tile: 32 w x 64 h per block. Phase1: uint4-load outHsw [w][h] -> fp32 LDS tile.
// Phase2: per thread 8 consecutive w: uint4 outW load, LDS-transposed outH, float4 x/out.
__global__ __launch_bounds__(256) void epilogue(const u16* __restrict__ outWbf,
                                                const u16* __restrict__ outHsw,
                                                const float* __restrict__ xe,
                                                const float* __restrict__ xq,
                                                const float* __restrict__ g1p,
                                                const float* __restrict__ g2p,
                                                float* __restrict__ out0,
                                                float* __restrict__ out1) {
  __shared__ float tile[32][65];      // [w][h] fp32
  int p = blockIdx.z;                 // b*512 + c
  int h0 = blockIdx.y * 64, w0 = blockIdx.x * 32;
  int t = threadIdx.x;
  {
    int w = t >> 3, hc = t & 7;       // 32 w x 8 h-chunks
    uint4 v = *reinterpret_cast<const uint4*>(
        &outHsw[(size_t)p * NHW + (size_t)(w0 + w) * 128 + h0 + hc * 8]);
    float f[8]; unpack8bf(v, f);
    for (int j = 0; j < 8; j++) tile[w][hc * 8 + j] = f[j];
  }
  __syncthreads();
  float g1 = g1p[0], g2 = g2p[0];
  int h = t >> 2, wc = t & 3;         // 64 h x 4 w-chunks (8 w each)
  size_t idx = (size_t)p * NHW + (size_t)(h0 + h) * 128 + w0 + wc * 8;
  uint4 wv = *reinterpret_cast<const uint4*>(&outWbf[idx]);
  float s[8]; unpack8bf(wv, s);
  float4 xe0 = *reinterpret_cast<const float4*>(&xe[idx]);
  float4 xe1 = *reinterpret_cast<const float4*>(&xe[idx + 4]);
  float4 xq0 = *reinterpret_cast<const float4*>(&xq[idx]);
  float4 xq1 = *reinterpret_cast<const float4*>(&xq[idx + 4]);
  float sum[8];
  for (int j = 0; j < 8; j++) sum[j] = s[j] + tile[wc * 8 + j][h] + 2.0f;
  float4 o0a = {g1 * sum[0] + xe0.x, g1 * sum[1] + xe0.y, g1 * sum[2] + xe0.z, g1 * sum[3] + xe0.w};
  float4 o0b = {g1 * sum[4] + xe1.x, g1 * sum[5] + xe1.y, g1 * sum[6] + xe1.z, g1 * sum[7] + xe1.w};
  float4 o1a = {g2 * sum[0] + xq0.x, g2 * sum[1] + xq0.y, g2 * sum[2] + xq0.z, g2 * sum[3] + xq0.w};
  float4 o1b = {g2 * sum[4] + xq1.x, g2 * sum[5] + xq1.y, g2 * sum[6] + xq1.z, g2 * sum[7] + xq1.w};
  *reinterpret_cast<float4*>(&out0[idx])     = o0a;
  *reinterpret_cast<float4*>(&out0[idx + 4]) = o0b;
  *reinterpret_cast<float4*>(&out1[idx])     = o1a;
  *reinterpret_cast<float4*>(&out1[idx + 4]) = o1b;
}

// ---------------------------------------------------------------------------
extern "C" void kernel_launch(void* const* d_in, const int* in_sizes, int n_in,
                              void* d_out, int out_size, void* d_ws, size_t ws_size,
                              hipStream_t stream) {
  (void)in_sizes; (void)n_in; (void)out_size; (void)ws_size;
  const float* xe = (const float*)d_in[0];
  const float* xq = (const float*)d_in[1];
  const float* Wq = (const float*)d_in[2];
  const float* bq = (const float*)d_in[3];
  const float* Wk = (const float*)d_in[4];
  const float* bk = (const float*)d_in[5];
  const float* Wv = (const float*)d_in[6];
  const float* bv = (const float*)d_in[7];
  const float* g1 = (const float*)d_in[8];
  const float* g2 = (const float*)d_in[9];
  float* out = (float*)d_out;

  char* ws = (char*)d_ws;
  u16* qT    = (u16*)(ws + 0);            //  8 MiB  (4,16384,64) bf16
  u16* kT    = (u16*)(ws + 8388608);      //  8 MiB
  u16* wv_bf = (u16*)(ws + 16777216);     //  512 KiB
  u16* wq_bf = (u16*)(ws + 17301504);     //  64 KiB
  u16* wk_bf = (u16*)(ws + 17367040);     //  64 KiB
  u16* v_n   = (u16*)(ws + 33554432);     // 64 MiB  (4,512,128,128) -> becomes outW bf16
  u16* v_sw  = (u16*)(ws + 100663296);    // 64 MiB  (b,c,w,h)       -> becomes outHsw bf16
  u16* att   = (u16*)(ws + 167772160);    // 32 MiB  (4,128,128,256)
  u16* xT    = (u16*)(ws + 201326592);    // 64 MiB  (b,hw,c) bf16: xeT then reused as xqT

  convert_w<<<dim3(128), 256, 0, stream>>>(Wv, wv_bf);
  convert_w<<<dim3(16), 256, 0, stream>>>(Wq, wq_bf);
  convert_w<<<dim3(16), 256, 0, stream>>>(Wk, wk_bf);
  transpose_cvt<<<dim3(512, 16, 4), 256, 0, stream>>>(xe, xT);          // xT = xeT
  proj64_mfma<<<dim3(128, 4), 256, 0, stream>>>(xT, wk_bf, bk, kT);
  proj_v_mfma<<<dim3(4, 128, 4), 256, 0, stream>>>(xT, wv_bf, bv, v_n);
  transpose_cvt<<<dim3(512, 16, 4), 256, 0, stream>>>(xq, xT);          // xT = xqT (xeT dead)
  proj64_mfma<<<dim3(128, 4), 256, 0, stream>>>(xT, wq_bf, bq, qT);
  transpose128<<<dim3(4, 4, 2048), 256, 0, stream>>>(v_n, v_sw);
  energy_mfma<<<dim3(128, 4), 256, 0, stream>>>(qT, kT, att, 0);
  energy_mfma<<<dim3(128, 4), 256, 0, stream>>>(qT, kT, att, 1);
  softmax_kern<<<dim3(16384), 256, 0, stream>>>(att);
  out_gemm_mfma<<<dim3(4, 128, 4), 256, 0, stream>>>(v_n, att, v_n, 0);   // in-place
  out_gemm_mfma<<<dim3(4, 128, 4), 256, 0, stream>>>(v_sw, att, v_sw, 1); // in-place
  epilogue<<<dim3(4, 2, 2048), 256, 0, stream>>>(v_n, v_sw, xe, xq, g1, g2,
                                                 out, out + 33554432);
}

// Round 4
// 748.210 us; speedup vs baseline: 1.8823x; 1.0304x over previous
//
#include <hip/hip_runtime.h>
#include <stdint.h>

typedef unsigned short u16;   // raw bf16 bits
typedef __attribute__((ext_vector_type(8))) short bf16x8;
typedef __attribute__((ext_vector_type(4))) float f32x4;

#define NB   4
#define NC   512
#define NC8  64
#define NH   128
#define NW   128
#define NHW  16384

__device__ __forceinline__ float b2f(u16 u) {
  union { float f; uint32_t i; } x; x.i = ((uint32_t)u) << 16; return x.f;
}
__device__ __forceinline__ u16 f2b(float f) {
  union { float f; uint32_t u; } x; x.f = f;
  uint32_t r = x.u + 0x7FFF + ((x.u >> 16) & 1);
  return (u16)(r >> 16);
}
__device__ __forceinline__ uint4 pack8bf(const float* f) {
  uint4 u;
  u.x = (uint32_t)f2b(f[0]) | ((uint32_t)f2b(f[1]) << 16);
  u.y = (uint32_t)f2b(f[2]) | ((uint32_t)f2b(f[3]) << 16);
  u.z = (uint32_t)f2b(f[4]) | ((uint32_t)f2b(f[5]) << 16);
  u.w = (uint32_t)f2b(f[6]) | ((uint32_t)f2b(f[7]) << 16);
  return u;
}
__device__ __forceinline__ void unpack8bf(uint4 u, float* f) {
  f[0] = b2f((u16)(u.x & 0xFFFF)); f[1] = b2f((u16)(u.x >> 16));
  f[2] = b2f((u16)(u.y & 0xFFFF)); f[3] = b2f((u16)(u.y >> 16));
  f[4] = b2f((u16)(u.z & 0xFFFF)); f[5] = b2f((u16)(u.z >> 16));
  f[6] = b2f((u16)(u.w & 0xFFFF)); f[7] = b2f((u16)(u.w >> 16));
}

// ---------------------------------------------------------------------------
// K0a: convert all three fp32 weight matrices -> bf16 in one launch.
// blocks [0,128) -> Wv (512x512), [128,144) -> Wq (64x512), [144,160) -> Wk.
__global__ __launch_bounds__(256) void convert_w3(const float* __restrict__ Wv,
                                                  const float* __restrict__ Wq,
                                                  const float* __restrict__ Wk,
                                                  u16* __restrict__ wv,
                                                  u16* __restrict__ wq,
                                                  u16* __restrict__ wk) {
  int bid = blockIdx.x;
  const float* W; u16* Wb; int base;
  if (bid < 128)      { W = Wv; Wb = wv; base = bid; }
  else if (bid < 144) { W = Wq; Wb = wq; base = bid - 128; }
  else                { W = Wk; Wb = wk; base = bid - 144; }
  int i = (base * 256 + threadIdx.x) * 8;
  float4 a = *reinterpret_cast<const float4*>(W + i);
  float4 b = *reinterpret_cast<const float4*>(W + i + 4);
  float f[8] = {a.x, a.y, a.z, a.w, b.x, b.y, b.z, b.w};
  *reinterpret_cast<uint4*>(Wb + i) = pack8bf(f);
}

// ---------------------------------------------------------------------------
// K0b: x (b, c=512, hw) fp32 -> xT (b, hw, c) bf16 for BOTH xe and xq.
// grid (256, 8, 8): z<4 -> xe (b=z), z>=4 -> xq (b=z-4). 64x64 tiles, fully vectorized.
__global__ __launch_bounds__(256) void transpose_cvt2(const float* __restrict__ xe,
                                                      const float* __restrict__ xq,
                                                      u16* __restrict__ xeT,
                                                      u16* __restrict__ xqT) {
  __shared__ float tile[64][68];     // [c][n], pad 4 keeps float4 16B-aligned
  int z = blockIdx.z;
  int b = z & 3;
  const float* x = (z < 4) ? xe : xq;
  u16* xT = (z < 4) ? xeT : xqT;
  int c0 = blockIdx.y * 64, n0 = blockIdx.x * 64;
  int t = threadIdx.x;
  const float* src = x + ((size_t)b * NC + c0) * NHW + n0;
  int r = t >> 2, cq = (t & 3) * 16;
#pragma unroll
  for (int v = 0; v < 4; v++) {
    float4 f = *reinterpret_cast<const float4*>(&src[(size_t)r * NHW + cq + v * 4]);
    *reinterpret_cast<float4*>(&tile[r][cq + v * 4]) = f;
  }
  __syncthreads();
  int n = t >> 2, cg = (t & 3) * 16;
  u16* dst = &xT[((size_t)b * NHW + n0 + n) * NC + c0 + cg];
#pragma unroll
  for (int half = 0; half < 2; half++) {
    float f[8];
#pragma unroll
    for (int j = 0; j < 8; j++) f[j] = tile[cg + half * 8 + j][n];
    *reinterpret_cast<uint4*>(dst + half * 8) = pack8bf(f);
  }
}

// ---------------------------------------------------------------------------
// K1: q AND k 64-channel projections via MFMA in one launch.
//   yT[b, hw, o(64)] = sum_c Wb[o,c] xT[b,hw,c] + bias.  grid (128, 2, 4): y=0 k, y=1 q.
__global__ __launch_bounds__(256) void proj64_qk(const u16* __restrict__ xeT,
                                                 const u16* __restrict__ xqT,
                                                 const u16* __restrict__ wk,
                                                 const u16* __restrict__ wq,
                                                 const float* __restrict__ bk,
                                                 const float* __restrict__ bq,
                                                 u16* __restrict__ kT,
                                                 u16* __restrict__ qT) {
  __shared__ __align__(16) u16 smem[12288];   // As 8KB | Bs 16KB ; out stage reuses
  char* AsB = (char*)smem;
  char* BsB = (char*)smem + 8192;
  int which = blockIdx.y;
  const u16* xT = which ? xqT : xeT;
  const u16* Wb = which ? wq : wk;
  const float* bias = which ? bq : bk;
  u16* yT = which ? qT : kT;
  int n0 = blockIdx.x * 128, b = blockIdx.z;
  int t = threadIdx.x;
  int wid = t >> 6, lane = t & 63;
  int wm = wid >> 1, wn = wid & 1;
  int l15 = lane & 15, lhi = lane >> 4;

  f32x4 acc[2][4];
#pragma unroll
  for (int m = 0; m < 2; m++)
#pragma unroll
    for (int n = 0; n < 4; n++)
#pragma unroll
      for (int r = 0; r < 4; r++) acc[m][n][r] = 0.f;

  const u16* Bbase = xT + ((size_t)b * NHW + n0) * NC;

  for (int c0 = 0; c0 < NC; c0 += 64) {
#pragma unroll
    for (int p = 0; p < 2; p++) {          // A: 64 rows x 64 K
      int idx = t + p * 256;
      int row = idx >> 3, cb = (idx & 7) * 8;
      int dst = row * 128 + ((cb * 2) ^ ((row & 7) << 4));
      bf16x8 av = *reinterpret_cast<const bf16x8*>(Wb + (size_t)row * NC + c0 + cb);
      *reinterpret_cast<bf16x8*>(AsB + dst) = av;
    }
#pragma unroll
    for (int p = 0; p < 4; p++) {          // B: 128 rows x 64 K
      int idx = t + p * 256;
      int row = idx >> 3, cb = (idx & 7) * 8;
      int dst = row * 128 + ((cb * 2) ^ ((row & 7) << 4));
      bf16x8 bv = *reinterpret_cast<const bf16x8*>(Bbase + (size_t)row * NC + c0 + cb);
      *reinterpret_cast<bf16x8*>(BsB + dst) = bv;
    }
    __syncthreads();
#pragma unroll
    for (int kk = 0; kk < 2; kk++) {
      int kbyte = kk * 64 + lhi * 16;
      bf16x8 af[2], bfr[4];
#pragma unroll
      for (int m = 0; m < 2; m++) {
        int row = wm * 32 + m * 16 + l15;
        af[m] = *reinterpret_cast<const bf16x8*>(AsB + row * 128 + (kbyte ^ ((row & 7) << 4)));
      }
#pragma unroll
      for (int n = 0; n < 4; n++) {
        int row = wn * 64 + n * 16 + l15;
        bfr[n] = *reinterpret_cast<const bf16x8*>(BsB + row * 128 + (kbyte ^ ((row & 7) << 4)));
      }
#pragma unroll
      for (int m = 0; m < 2; m++)
#pragma unroll
        for (int n = 0; n < 4; n++)
          acc[m][n] = __builtin_amdgcn_mfma_f32_16x16x32_bf16(af[m], bfr[n], acc[m][n], 0, 0, 0);
    }
    __syncthreads();
  }

  char* stage = (char*)smem;
#pragma unroll
  for (int m = 0; m < 2; m++) {
#pragma unroll
    for (int r = 0; r < 4; r++) {
      int o = wm * 32 + m * 16 + lhi * 4 + r;
      float bval = bias[o];
#pragma unroll
      for (int n = 0; n < 4; n++) {
        int col = wn * 64 + n * 16 + l15;
        int byte = col * 128 + ((o * 2) ^ ((col & 7) << 4));
        *reinterpret_cast<u16*>(stage + byte) = f2b(acc[m][n][r] + bval);
      }
    }
  }
  __syncthreads();
#pragma unroll
  for (int p = 0; p < 4; p++) {
    int idx = t + p * 256;
    int col = idx >> 3, seg = idx & 7;
    int byte = col * 128 + ((seg * 16) ^ ((col & 7) << 4));
    uint4 v = *reinterpret_cast<const uint4*>(stage + byte);
    *reinterpret_cast<uint4*>(&yT[((size_t)b * NHW + n0 + col) * 64 + seg * 8]) = v;
  }
}

// ---------------------------------------------------------------------------
// K2: 512-channel projection (v) via MFMA bf16. (proven)
__global__ __launch_bounds__(256) void proj_v_mfma(const u16* __restrict__ xT,
                                                   const u16* __restrict__ Wb,
                                                   const float* __restrict__ bias,
                                                   u16* __restrict__ y) {
  __shared__ __align__(16) u16 smem[16384];
  char* AsB = (char*)smem;
  char* BsB = (char*)(smem + 8192);
  int o0 = blockIdx.x * 128, n0 = blockIdx.y * 128, b = blockIdx.z;
  int t = threadIdx.x;
  int wid = t >> 6, lane = t & 63;
  int wm = wid >> 1, wn = wid & 1;
  int l15 = lane & 15, lhi = lane >> 4;

  f32x4 acc[4][4];
#pragma unroll
  for (int m = 0; m < 4; m++)
#pragma unroll
    for (int n = 0; n < 4; n++)
#pragma unroll
      for (int r = 0; r < 4; r++) acc[m][n][r] = 0.f;

  const u16* Arow = Wb + (size_t)o0 * NC;
  const u16* Brow = xT + ((size_t)b * NHW + n0) * NC;

  for (int c0 = 0; c0 < NC; c0 += 64) {
#pragma unroll
    for (int p = 0; p < 4; p++) {
      int idx = t + p * 256;
      int row = idx >> 3;
      int cb  = (idx & 7) * 8;
      int dst = row * 128 + ((cb * 2) ^ ((row & 7) << 4));
      bf16x8 av = *reinterpret_cast<const bf16x8*>(Arow + (size_t)row * NC + c0 + cb);
      *reinterpret_cast<bf16x8*>(AsB + dst) = av;
      bf16x8 bv = *reinterpret_cast<const bf16x8*>(Brow + (size_t)row * NC + c0 + cb);
      *reinterpret_cast<bf16x8*>(BsB + dst) = bv;
    }
    __syncthreads();
#pragma unroll
    for (int kk = 0; kk < 2; kk++) {
      int kbyte = kk * 64 + lhi * 16;
      bf16x8 af[4], bfr[4];
#pragma unroll
      for (int m = 0; m < 4; m++) {
        int row = wm * 64 + m * 16 + l15;
        af[m] = *reinterpret_cast<const bf16x8*>(AsB + row * 128 + (kbyte ^ ((row & 7) << 4)));
      }
#pragma unroll
      for (int n = 0; n < 4; n++) {
        int row = wn * 64 + n * 16 + l15;
        bfr[n] = *reinterpret_cast<const bf16x8*>(BsB + row * 128 + (kbyte ^ ((row & 7) << 4)));
      }
#pragma unroll
      for (int m = 0; m < 4; m++)
#pragma unroll
        for (int n = 0; n < 4; n++)
          acc[m][n] = __builtin_amdgcn_mfma_f32_16x16x32_bf16(af[m], bfr[n], acc[m][n], 0, 0, 0);
    }
    __syncthreads();
  }

  char* stage = (char*)smem + wid * 8192;
#pragma unroll
  for (int m = 0; m < 4; m++) {
#pragma unroll
    for (int r = 0; r < 4; r++) {
      int lrow = m * 16 + lhi * 4 + r;
      float bval = bias[o0 + wm * 64 + lrow];
#pragma unroll
      for (int n = 0; n < 4; n++) {
        int col = n * 16 + l15;
        *reinterpret_cast<u16*>(stage + lrow * 128 + col * 2) = f2b(acc[m][n][r] + bval);
      }
    }
  }
  __syncthreads();
#pragma unroll
  for (int s = 0; s < 8; s++) {
    int row  = s * 8 + (lane >> 3);
    int colb = (lane & 7) * 8;
    uint4 v = *reinterpret_cast<const uint4*>(stage + row * 128 + colb * 2);
    size_t addr = ((size_t)b * NC + o0 + wm * 64 + row) * (size_t)NHW + n0 + wn * 64 + colb;
    *reinterpret_cast<uint4*>(&y[addr]) = v;
  }
}

// ---------------------------------------------------------------------------
// K3: transpose last two dims of (planes,128,128) bf16, 64x64 tiles, vectorized.
__global__ __launch_bounds__(256) void transpose128v(const u16* __restrict__ src,
                                                     u16* __restrict__ dst) {
  __shared__ u16 tile[64][68];       // 136B rows (8B aligned)
  int p = blockIdx.z;
  int i0 = blockIdx.y * 64, j0 = blockIdx.x * 64;
  int t = threadIdx.x;
  const u16* s = src + (size_t)p * NHW;
  u16* d = dst + (size_t)p * NHW;
#pragma unroll
  for (int q = 0; q < 2; q++) {
    int idx = t + q * 256;
    int r = idx >> 3, c8 = (idx & 7) * 8;
    uint4 v = *reinterpret_cast<const uint4*>(&s[(size_t)(i0 + r) * 128 + j0 + c8]);
    *reinterpret_cast<uint2*>(&tile[r][c8])     = make_uint2(v.x, v.y);
    *reinterpret_cast<uint2*>(&tile[r][c8 + 4]) = make_uint2(v.z, v.w);
  }
  __syncthreads();
#pragma unroll
  for (int q = 0; q < 2; q++) {
    int idx = t + q * 256;
    int j = idx >> 3, c8 = (idx & 7) * 8;
    u16 f[8];
#pragma unroll
    for (int v = 0; v < 8; v++) f[v] = tile[c8 + v][j];
    uint4 o;
    o.x = (uint32_t)f[0] | ((uint32_t)f[1] << 16);
    o.y = (uint32_t)f[2] | ((uint32_t)f[3] << 16);
    o.z = (uint32_t)f[4] | ((uint32_t)f[5] << 16);
    o.w = (uint32_t)f[6] | ((uint32_t)f[7] << 16);
    *reinterpret_cast<uint4*>(&d[(size_t)(j0 + j) * 128 + i0 + c8]) = o;
  }
}

// ---------------------------------------------------------------------------
// K4: BOTH energies via MFMA in one launch. grid (128, 4, 2): z = isH.
__global__ __launch_bounds__(256) void energy2(const u16* __restrict__ QT,
                                               const u16* __restrict__ KT,
                                               u16* __restrict__ att) {
  __shared__ __align__(16) u16 smem[16384];
  char* AsB = (char*)smem;
  char* BsB = (char*)(smem + 8192);
  int s = blockIdx.x, b = blockIdx.y, isH = blockIdx.z;
  int t = threadIdx.x;
  int wid = t >> 6, lane = t & 63;
  int wm = wid >> 1, wn = wid & 1;
  int l15 = lane & 15, lhi = lane >> 4;

  size_t base = (size_t)b * NHW * 64;
  size_t rowstride = isH ? (size_t)128 * 64 : 64;
  size_t off0 = isH ? (size_t)s * 64 : (size_t)s * 128 * 64;

  f32x4 acc[4][4];
#pragma unroll
  for (int m = 0; m < 4; m++)
#pragma unroll
    for (int n = 0; n < 4; n++)
#pragma unroll
      for (int r = 0; r < 4; r++) acc[m][n][r] = 0.f;

#pragma unroll
  for (int p = 0; p < 4; p++) {
    int idx = t + p * 256;
    int row = idx >> 3;
    int cb  = (idx & 7) * 8;
    int dst = row * 128 + ((cb * 2) ^ ((row & 7) << 4));
    bf16x8 av = *reinterpret_cast<const bf16x8*>(QT + base + off0 + (size_t)row * rowstride + cb);
    *reinterpret_cast<bf16x8*>(AsB + dst) = av;
    bf16x8 bv = *reinterpret_cast<const bf16x8*>(KT + base + off0 + (size_t)row * rowstride + cb);
    *reinterpret_cast<bf16x8*>(BsB + dst) = bv;
  }
  __syncthreads();
#pragma unroll
  for (int kk = 0; kk < 2; kk++) {
    int kbyte = kk * 64 + lhi * 16;
    bf16x8 af[4], bfr[4];
#pragma unroll
    for (int m = 0; m < 4; m++) {
      int row = wm * 64 + m * 16 + l15;
      af[m] = *reinterpret_cast<const bf16x8*>(AsB + row * 128 + (kbyte ^ ((row & 7) << 4)));
    }
#pragma unroll
    for (int n = 0; n < 4; n++) {
      int row = wn * 64 + n * 16 + l15;
      bfr[n] = *reinterpret_cast<const bf16x8*>(BsB + row * 128 + (kbyte ^ ((row & 7) << 4)));
    }
#pragma unroll
    for (int m = 0; m < 4; m++)
#pragma unroll
      for (int n = 0; n < 4; n++)
        acc[m][n] = __builtin_amdgcn_mfma_f32_16x16x32_bf16(af[m], bfr[n], acc[m][n], 0, 0, 0);
  }
  __syncthreads();

  char* stage = (char*)smem + wid * 8192;
#pragma unroll
  for (int m = 0; m < 4; m++) {
#pragma unroll
    for (int r = 0; r < 4; r++) {
      int lrow = m * 16 + lhi * 4 + r;
      int grow = wm * 64 + lrow;
#pragma unroll
      for (int n = 0; n < 4; n++) {
        int col = n * 16 + l15;
        int gcol = wn * 64 + col;
        float v = acc[m][n][r];
        if (isH && gcol == grow) v = -1e30f;
        *reinterpret_cast<u16*>(stage + lrow * 128 + col * 2) = f2b(v);
      }
    }
  }
  __syncthreads();
  size_t attb = (size_t)b * 4194304;
#pragma unroll
  for (int sb = 0; sb < 8; sb++) {
    int row  = wm * 64 + sb * 8 + (lane >> 3);
    int colb = wn * 64 + (lane & 7) * 8;
    uint4 v = *reinterpret_cast<const uint4*>(stage + (sb * 8 + (lane >> 3)) * 128 + (lane & 7) * 16);
    size_t addr = attb + (isH ? ((size_t)row * 32768 + (size_t)s * 256 + colb)
                              : ((size_t)s * 32768 + (size_t)row * 256 + 128 + colb));
    *reinterpret_cast<uint4*>(&att[addr]) = v;
  }
}

// ---------------------------------------------------------------------------
// K5: softmax over 256-entry rows, in place. 32 lanes per row, 8 rows/block.
__global__ __launch_bounds__(256) void softmax_kern(u16* __restrict__ att) {
  int half = threadIdx.x >> 5;        // 0..7
  int lane = threadIdx.x & 31;
  size_t row = (size_t)blockIdx.x * 8 + half;
  u16* p = att + row * 256;
  uint4 u = *reinterpret_cast<const uint4*>(&p[lane * 8]);
  float v[8]; unpack8bf(u, v);
  float mx = v[0];
  for (int i = 1; i < 8; i++) mx = fmaxf(mx, v[i]);
  for (int off = 16; off; off >>= 1) mx = fmaxf(mx, __shfl_xor(mx, off));
  float sum = 0.f;
  for (int i = 0; i < 8; i++) { v[i] = __expf(v[i] - mx); sum += v[i]; }
  for (int off = 16; off; off >>= 1) sum += __shfl_xor(sum, off);
  float inv = 1.f / sum;
  for (int i = 0; i < 8; i++) v[i] *= inv;
  *reinterpret_cast<uint4*>(&p[lane * 8]) = pack8bf(v);
}

// ---------------------------------------------------------------------------
// K6: BOTH output GEMMs via MFMA, in-place, one launch. grid (4,128,8): z = b + 4*isH.
__global__ __launch_bounds__(256) void out_gemm2(const u16* __restrict__ Vn,
                                                 const u16* __restrict__ Vsw,
                                                 const u16* __restrict__ att) {
  __shared__ __align__(16) u16 smem[16384];
  char* AsB = (char*)smem;
  char* BsB = (char*)(smem + 8192);
  int ct = blockIdx.x, s = blockIdx.y;
  int b = blockIdx.z & 3, isH = blockIdx.z >> 2;
  const u16* V = isH ? Vsw : Vn;
  u16* out = const_cast<u16*>(V);          // in-place (each block owns its tile)
  int t = threadIdx.x;
  int wid = t >> 6, lane = t & 63;
  int wm = wid >> 1, wn = wid & 1;
  int l15 = lane & 15, lhi = lane >> 4;

  f32x4 acc[4][4];
#pragma unroll
  for (int m = 0; m < 4; m++)
#pragma unroll
    for (int n = 0; n < 4; n++)
#pragma unroll
      for (int r = 0; r < 4; r++) acc[m][n][r] = 0.f;

  const u16* Abase = V + ((size_t)(b * NC + ct * 128)) * NHW + (size_t)s * 128;
  size_t attb = (size_t)b * 4194304;
  size_t bbase = attb + (isH ? (size_t)s * 256 : (size_t)s * 32768 + 128);
  size_t bstride = isH ? 32768 : 256;

  for (int c0 = 0; c0 < 128; c0 += 64) {
#pragma unroll
    for (int p = 0; p < 4; p++) {
      int idx = t + p * 256;
      int row = idx >> 3;
      int cb  = (idx & 7) * 8;
      int dst = row * 128 + ((cb * 2) ^ ((row & 7) << 4));
      bf16x8 av = *reinterpret_cast<const bf16x8*>(Abase + (size_t)row * NHW + c0 + cb);
      *reinterpret_cast<bf16x8*>(AsB + dst) = av;
      bf16x8 bv = *reinterpret_cast<const bf16x8*>(att + bbase + (size_t)row * bstride + c0 + cb);
      *reinterpret_cast<bf16x8*>(BsB + dst) = bv;
    }
    __syncthreads();
#pragma unroll
    for (int kk = 0; kk < 2; kk++) {
      int kbyte = kk * 64 + lhi * 16;
      bf16x8 af[4], bfr[4];
#pragma unroll
      for (int m = 0; m < 4; m++) {
        int row = wm * 64 + m * 16 + l15;
        af[m] = *reinterpret_cast<const bf16x8*>(AsB + row * 128 + (kbyte ^ ((row & 7) << 4)));
      }
#pragma unroll
      for (int n = 0; n < 4; n++) {
        int row = wn * 64 + n * 16 + l15;
        bfr[n] = *reinterpret_cast<const bf16x8*>(BsB + row * 128 + (kbyte ^ ((row & 7) << 4)));
      }
#pragma unroll
      for (int m = 0; m < 4; m++)
#pragma unroll
        for (int n = 0; n < 4; n++)
          acc[m][n] = __builtin_amdgcn_mfma_f32_16x16x32_bf16(af[m], bfr[n], acc[m][n], 0, 0, 0);
    }
    __syncthreads();
  }

  char* stage = (char*)smem + wid * 8192;
#pragma unroll
  for (int m = 0; m < 4; m++) {
#pragma unroll
    for (int r = 0; r < 4; r++) {
      int lrow = m * 16 + lhi * 4 + r;
#pragma unroll
      for (int n = 0; n < 4; n++) {
        int col = n * 16 + l15;
        *reinterpret_cast<u16*>(stage + lrow * 128 + col * 2) = f2b(acc[m][n][r]);
      }
    }
  }
  __syncthreads();
#pragma unroll
  for (int sb = 0; sb < 8; sb++) {
    int row  = sb * 8 + (lane >> 3);
    int colb = (lane & 7) * 8;
    uint4 v = *reinterpret_cast<const uint4*>(stage + row * 128 + colb * 2);
    size_t addr = ((size_t)(b * NC + ct * 128 + wm * 64 + row)) * NHW + (size_t)s * 128 + wn * 64 + colb;
    *reinterpret_cast<uint4*>(&out[addr]) = v;
  }
}

// ---------------------------------------------------------------------------
// K7: epilogue, fully vectorized (proven).
__global__ __launch_bounds__(256) void epilogue(const u16* __restrict__ outWbf,
                                                const u16* __restrict__ outHsw,
                                                const float* __restrict__ xe,
                                                const float* __restrict__ xq,
                                                const float* __restrict__ g1p,
                                                const float* __restrict__ g2p,
                                                float* __restrict__ out0,
                                                float* __restrict__ out1) {
  __shared__ float tile[32][65];      // [w][h] fp32
  int p = blockIdx.z;                 // b*512 + c
  int h0 = blockIdx.y * 64, w0 = blockIdx.x * 32;
  int t = threadIdx.x;
  {
    int w = t >> 3, hc = t & 7;
    uint4 v = *reinterpret_cast<const uint4*>(
        &outHsw[(size_t)p * NHW + (size_t)(w0 + w) * 128 + h0 + hc * 8]);
    float f[8]; unpack8bf(v, f);
    for (int j = 0; j < 8; j++) tile[w][hc * 8 + j] = f[j];
  }
  __syncthreads();
  float g1 = g1p[0], g2 = g2p[0];
  int h = t >> 2, wc = t & 3;
  size_t idx = (size_t)p * NHW + (size_t)(h0 + h) * 128 + w0 + wc * 8;
  uint4 wv = *reinterpret_cast<const uint4*>(&outWbf[idx]);
  float s[8]; unpack8bf(wv, s);
  float4 xe0 = *reinterpret_cast<const float4*>(&xe[idx]);
  float4 xe1 = *reinterpret_cast<const float4*>(&xe[idx + 4]);
  float4 xq0 = *reinterpret_cast<const float4*>(&xq[idx]);
  float4 xq1 = *reinterpret_cast<const float4*>(&xq[idx + 4]);
  float sum[8];
  for (int j = 0; j < 8; j++) sum[j] = s[j] + tile[wc * 8 + j][h] + 2.0f;
  float4 o0a = {g1 * sum[0] + xe0.x, g1 * sum[1] + xe0.y, g1 * sum[2] + xe0.z, g1 * sum[3] + xe0.w};
  float4 o0b = {g1 * sum[4] + xe1.x, g1 * sum[5] + xe1.y, g1 * sum[6] + xe1.z, g1 * sum[7] + xe1.w};
  float4 o1a = {g2 * sum[0] + xq0.x, g2 * sum[1] + xq0.y, g2 * sum[2] + xq0.z, g2 * sum[3] + xq0.w};
  float4 o1b = {g2 * sum[4] + xq1.x, g2 * sum[5] + xq1.y, g2 * sum[6] + xq1.z, g2 * sum[7] + xq1.w};
  *reinterpret_cast<float4*>(&out0[idx])     = o0a;
  *reinterpret_cast<float4*>(&out0[idx + 4]) = o0b;
  *reinterpret_cast<float4*>(&out1[idx])     = o1a;
  *reinterpret_cast<float4*>(&out1[idx + 4]) = o1b;
}

// ---------------------------------------------------------------------------
extern "C" void kernel_launch(void* const* d_in, const int* in_sizes, int n_in,
                              void* d_out, int out_size, void* d_ws, size_t ws_size,
                              hipStream_t stream) {
  (void)in_sizes; (void)n_in; (void)out_size; (void)ws_size;
  const float* xe = (const float*)d_in[0];
  const float* xq = (const float*)d_in[1];
  const float* Wq = (const float*)d_in[2];
  const float* bq = (const float*)d_in[3];
  const float* Wk = (const float*)d_in[4];
  const float* bk = (const float*)d_in[5];
  const float* Wv = (const float*)d_in[6];
  const float* bv = (const float*)d_in[7];
  const float* g1 = (const float*)d_in[8];
  const float* g2 = (const float*)d_in[9];
  float* out = (float*)d_out;

  char* ws = (char*)d_ws;
  u16* qT    = (u16*)(ws + 0);            //  8 MiB  (4,16384,64) bf16
  u16* kT    = (u16*)(ws + 8388608);      //  8 MiB
  u16* wv_bf = (u16*)(ws + 16777216);     //  512 KiB
  u16* wq_bf = (u16*)(ws + 17301504);     //  64 KiB
  u16* wk_bf = (u16*)(ws + 17367040);     //  64 KiB
  u16* v_n   = (u16*)(ws + 33554432);     // 64 MiB  (4,512,128,128) -> becomes outW bf16
  u16* v_sw  = (u16*)(ws + 100663296);    // 64 MiB  (b,c,w,h)       -> becomes outHsw bf16
  u16* att   = (u16*)(ws + 167772160);    // 32 MiB  (4,128,128,256)
  u16* xeT   = (u16*)(ws + 201326592);    // 64 MiB  (b,hw,c) bf16
  u16* xqT   = (u16*)(ws + 100663296);    // 64 MiB  in v_sw slot (v_sw written later)

  convert_w3<<<dim3(160), 256, 0, stream>>>(Wv, Wq, Wk, wv_bf, wq_bf, wk_bf);
  transpose_cvt2<<<dim3(256, 8, 8), 256, 0, stream>>>(xe, xq, xeT, xqT);
  proj64_qk<<<dim3(128, 2, 4), 256, 0, stream>>>(xeT, xqT, wk_bf, wq_bf, bk, bq, kT, qT);
  proj_v_mfma<<<dim3(4, 128, 4), 256, 0, stream>>>(xeT, wv_bf, bv, v_n);
  transpose128v<<<dim3(2, 2, 2048), 256, 0, stream>>>(v_n, v_sw);   // overwrites xqT (dead)
  energy2<<<dim3(128, 4, 2), 256, 0, stream>>>(qT, kT, att);
  softmax_kern<<<dim3(8192), 256, 0, stream>>>(att);
  out_gemm2<<<dim3(4, 128, 8), 256, 0, stream>>>(v_n, v_sw, att);   // in-place
  epilogue<<<dim3(4, 2, 2048), 256, 0, stream>>>(v_n, v_sw, xe, xq, g1, g2,
                                                 out, out + 33554432);
}

// Round 6
// 724.874 us; speedup vs baseline: 1.9428x; 1.0322x over previous
//
#include <hip/hip_runtime.h>
#include <stdint.h>

typedef unsigned short u16;   // raw bf16 bits
typedef __attribute__((ext_vector_type(8))) short bf16x8;
typedef __attribute__((ext_vector_type(4))) float f32x4;

#define NB   4
#define NC   512
#define NC8  64
#define NH   128
#define NW   128
#define NHW  16384

__device__ __forceinline__ float b2f(u16 u) {
  union { float f; uint32_t i; } x; x.i = ((uint32_t)u) << 16; return x.f;
}
__device__ __forceinline__ u16 f2b(float f) {
  union { float f; uint32_t u; } x; x.f = f;
  uint32_t r = x.u + 0x7FFF + ((x.u >> 16) & 1);
  return (u16)(r >> 16);
}
__device__ __forceinline__ uint4 pack8bf(const float* f) {
  uint4 u;
  u.x = (uint32_t)f2b(f[0]) | ((uint32_t)f2b(f[1]) << 16);
  u.y = (uint32_t)f2b(f[2]) | ((uint32_t)f2b(f[3]) << 16);
  u.z = (uint32_t)f2b(f[4]) | ((uint32_t)f2b(f[5]) << 16);
  u.w = (uint32_t)f2b(f[6]) | ((uint32_t)f2b(f[7]) << 16);
  return u;
}
__device__ __forceinline__ void unpack8bf(uint4 u, float* f) {
  f[0] = b2f((u16)(u.x & 0xFFFF)); f[1] = b2f((u16)(u.x >> 16));
  f[2] = b2f((u16)(u.y & 0xFFFF)); f[3] = b2f((u16)(u.y >> 16));
  f[4] = b2f((u16)(u.z & 0xFFFF)); f[5] = b2f((u16)(u.z >> 16));
  f[6] = b2f((u16)(u.w & 0xFFFF)); f[7] = b2f((u16)(u.w >> 16));
}

// ---------------------------------------------------------------------------
// K0: x (b, c=512, hw) fp32 -> xT (b, hw, c) bf16 for BOTH xe and xq,
//     PLUS (z==8 slice) all three weight conversions fp32->bf16.
// grid (256, 8, 9).
__global__ __launch_bounds__(256) void transpose_cvt2(const float* __restrict__ xe,
                                                      const float* __restrict__ xq,
                                                      u16* __restrict__ xeT,
                                                      u16* __restrict__ xqT,
                                                      const float* __restrict__ Wv,
                                                      const float* __restrict__ Wq,
                                                      const float* __restrict__ Wk,
                                                      u16* __restrict__ wv,
                                                      u16* __restrict__ wq,
                                                      u16* __restrict__ wk) {
  __shared__ float tile[64][68];     // [c][n], pad 4 keeps float4 16B-aligned
  int z = blockIdx.z;
  if (z == 8) {                       // weight-conversion slice
    int bid = blockIdx.y * 256 + blockIdx.x;
    if (bid >= 160) return;
    const float* W; u16* Wb; int base;
    if (bid < 128)      { W = Wv; Wb = wv; base = bid; }
    else if (bid < 144) { W = Wq; Wb = wq; base = bid - 128; }
    else                { W = Wk; Wb = wk; base = bid - 144; }
    int i = (base * 256 + threadIdx.x) * 8;
    float4 a = *reinterpret_cast<const float4*>(W + i);
    float4 b = *reinterpret_cast<const float4*>(W + i + 4);
    float f[8] = {a.x, a.y, a.z, a.w, b.x, b.y, b.z, b.w};
    *reinterpret_cast<uint4*>(Wb + i) = pack8bf(f);
    return;
  }
  int b = z & 3;
  const float* x = (z < 4) ? xe : xq;
  u16* xT = (z < 4) ? xeT : xqT;
  int c0 = blockIdx.y * 64, n0 = blockIdx.x * 64;
  int t = threadIdx.x;
  const float* src = x + ((size_t)b * NC + c0) * NHW + n0;
  int r = t >> 2, cq = (t & 3) * 16;
#pragma unroll
  for (int v = 0; v < 4; v++) {
    float4 f = *reinterpret_cast<const float4*>(&src[(size_t)r * NHW + cq + v * 4]);
    *reinterpret_cast<float4*>(&tile[r][cq + v * 4]) = f;
  }
  __syncthreads();
  int n = t >> 2, cg = (t & 3) * 16;
  u16* dst = &xT[((size_t)b * NHW + n0 + n) * NC + c0 + cg];
#pragma unroll
  for (int half = 0; half < 2; half++) {
    float f[8];
#pragma unroll
    for (int j = 0; j < 8; j++) f[j] = tile[cg + half * 8 + j][n];
    *reinterpret_cast<uint4*>(dst + half * 8) = pack8bf(f);
  }
}

// ---------------------------------------------------------------------------
// K1: q AND k 64-channel projections via MFMA, pipelined (issue-early).
//   yT[b, hw, o(64)] = sum_c Wb[o,c] xT[b,hw,c] + bias.  grid (128, 2, 4).
__global__ __launch_bounds__(256) void proj64_qk(const u16* __restrict__ xeT,
                                                 const u16* __restrict__ xqT,
                                                 const u16* __restrict__ wk,
                                                 const u16* __restrict__ wq,
                                                 const float* __restrict__ bk,
                                                 const float* __restrict__ bq,
                                                 u16* __restrict__ kT,
                                                 u16* __restrict__ qT) {
  __shared__ __align__(16) u16 smem[12288];   // As 8KB | Bs 16KB ; out stage reuses
  char* AsB = (char*)smem;
  char* BsB = (char*)smem + 8192;
  int which = blockIdx.y;
  const u16* xT = which ? xqT : xeT;
  const u16* Wb = which ? wq : wk;
  const float* bias = which ? bq : bk;
  u16* yT = which ? qT : kT;
  int n0 = blockIdx.x * 128, b = blockIdx.z;
  int t = threadIdx.x;
  int wid = t >> 6, lane = t & 63;
  int wm = wid >> 1, wn = wid & 1;
  int l15 = lane & 15, lhi = lane >> 4;

  f32x4 acc[2][4];
#pragma unroll
  for (int m = 0; m < 2; m++)
#pragma unroll
    for (int n = 0; n < 4; n++)
#pragma unroll
      for (int r = 0; r < 4; r++) acc[m][n][r] = 0.f;

  const u16* Bbase = xT + ((size_t)b * NHW + n0) * NC;

  // staging registers
  bf16x8 ar[2], br[4];
#pragma unroll
  for (int p = 0; p < 2; p++) {
    int idx = t + p * 256;
    int row = idx >> 3, cb = (idx & 7) * 8;
    ar[p] = *reinterpret_cast<const bf16x8*>(Wb + (size_t)row * NC + cb);
  }
#pragma unroll
  for (int p = 0; p < 4; p++) {
    int idx = t + p * 256;
    int row = idx >> 3, cb = (idx & 7) * 8;
    br[p] = *reinterpret_cast<const bf16x8*>(Bbase + (size_t)row * NC + cb);
  }

  for (int tt = 0; tt < 8; tt++) {
#pragma unroll
    for (int p = 0; p < 2; p++) {          // write A regs -> LDS
      int idx = t + p * 256;
      int row = idx >> 3, cb = (idx & 7) * 8;
      int dst = row * 128 + ((cb * 2) ^ ((row & 7) << 4));
      *reinterpret_cast<bf16x8*>(AsB + dst) = ar[p];
    }
#pragma unroll
    for (int p = 0; p < 4; p++) {          // write B regs -> LDS
      int idx = t + p * 256;
      int row = idx >> 3, cb = (idx & 7) * 8;
      int dst = row * 128 + ((cb * 2) ^ ((row & 7) << 4));
      *reinterpret_cast<bf16x8*>(BsB + dst) = br[p];
    }
    __syncthreads();
    if (tt < 7) {                          // issue next-tile loads (overlap compute)
      int c0 = (tt + 1) * 64;
#pragma unroll
      for (int p = 0; p < 2; p++) {
        int idx = t + p * 256;
        int row = idx >> 3, cb = (idx & 7) * 8;
        ar[p] = *reinterpret_cast<const bf16x8*>(Wb + (size_t)row * NC + c0 + cb);
      }
#pragma unroll
      for (int p = 0; p < 4; p++) {
        int idx = t + p * 256;
        int row = idx >> 3, cb = (idx & 7) * 8;
        br[p] = *reinterpret_cast<const bf16x8*>(Bbase + (size_t)row * NC + c0 + cb);
      }
    }
#pragma unroll
    for (int kk = 0; kk < 2; kk++) {
      int kbyte = kk * 64 + lhi * 16;
      bf16x8 af[2], bfr[4];
#pragma unroll
      for (int m = 0; m < 2; m++) {
        int row = wm * 32 + m * 16 + l15;
        af[m] = *reinterpret_cast<const bf16x8*>(AsB + row * 128 + (kbyte ^ ((row & 7) << 4)));
      }
#pragma unroll
      for (int n = 0; n < 4; n++) {
        int row = wn * 64 + n * 16 + l15;
        bfr[n] = *reinterpret_cast<const bf16x8*>(BsB + row * 128 + (kbyte ^ ((row & 7) << 4)));
      }
#pragma unroll
      for (int m = 0; m < 2; m++)
#pragma unroll
        for (int n = 0; n < 4; n++)
          acc[m][n] = __builtin_amdgcn_mfma_f32_16x16x32_bf16(af[m], bfr[n], acc[m][n], 0, 0, 0);
    }
    __syncthreads();
  }

  char* stage = (char*)smem;
#pragma unroll
  for (int m = 0; m < 2; m++) {
#pragma unroll
    for (int r = 0; r < 4; r++) {
      int o = wm * 32 + m * 16 + lhi * 4 + r;
      float bval = bias[o];
#pragma unroll
      for (int n = 0; n < 4; n++) {
        int col = wn * 64 + n * 16 + l15;
        int byte = col * 128 + ((o * 2) ^ ((col & 7) << 4));
        *reinterpret_cast<u16*>(stage + byte) = f2b(acc[m][n][r] + bval);
      }
    }
  }
  __syncthreads();
#pragma unroll
  for (int p = 0; p < 4; p++) {
    int idx = t + p * 256;
    int col = idx >> 3, seg = idx & 7;
    int byte = col * 128 + ((seg * 16) ^ ((col & 7) << 4));
    uint4 v = *reinterpret_cast<const uint4*>(stage + byte);
    *reinterpret_cast<uint4*>(&yT[((size_t)b * NHW + n0 + col) * 64 + seg * 8]) = v;
  }
}

// ---------------------------------------------------------------------------
// K2: 512-channel projection (v) via MFMA, pipelined + XCD-chunked swizzle.
// grid (4, 128, 4) = 2048 wg; logical = (lin%8)*256 + lin/8.
__global__ __launch_bounds__(256) void proj_v_mfma(const u16* __restrict__ xT,
                                                   const u16* __restrict__ Wb,
                                                   const float* __restrict__ bias,
                                                   u16* __restrict__ y) {
  __shared__ __align__(16) u16 smem[16384];
  char* AsB = (char*)smem;
  char* BsB = (char*)(smem + 8192);
  int lin = blockIdx.x + (blockIdx.y << 2) + (blockIdx.z << 9);
  int l = ((lin & 7) << 8) + (lin >> 3);     // bijective: 2048 % 8 == 0
  int o0 = (l & 3) * 128;
  int n0 = ((l >> 2) & 127) * 128;
  int b  = l >> 9;
  int t = threadIdx.x;
  int wid = t >> 6, lane = t & 63;
  int wm = wid >> 1, wn = wid & 1;
  int l15 = lane & 15, lhi = lane >> 4;

  f32x4 acc[4][4];
#pragma unroll
  for (int m = 0; m < 4; m++)
#pragma unroll
    for (int n = 0; n < 4; n++)
#pragma unroll
      for (int r = 0; r < 4; r++) acc[m][n][r] = 0.f;

  const u16* Arow = Wb + (size_t)o0 * NC;
  const u16* Brow = xT + ((size_t)b * NHW + n0) * NC;

  bf16x8 ar[4], br[4];
#pragma unroll
  for (int p = 0; p < 4; p++) {
    int idx = t + p * 256;
    int row = idx >> 3, cb = (idx & 7) * 8;
    ar[p] = *reinterpret_cast<const bf16x8*>(Arow + (size_t)row * NC + cb);
    br[p] = *reinterpret_cast<const bf16x8*>(Brow + (size_t)row * NC + cb);
  }

  for (int tt = 0; tt < 8; tt++) {
#pragma unroll
    for (int p = 0; p < 4; p++) {
      int idx = t + p * 256;
      int row = idx >> 3, cb = (idx & 7) * 8;
      int dst = row * 128 + ((cb * 2) ^ ((row & 7) << 4));
      *reinterpret_cast<bf16x8*>(AsB + dst) = ar[p];
      *reinterpret_cast<bf16x8*>(BsB + dst) = br[p];
    }
    __syncthreads();
    if (tt < 7) {
      int c0 = (tt + 1) * 64;
#pragma unroll
      for (int p = 0; p < 4; p++) {
        int idx = t + p * 256;
        int row = idx >> 3, cb = (idx & 7) * 8;
        ar[p] = *reinterpret_cast<const bf16x8*>(Arow + (size_t)row * NC + c0 + cb);
        br[p] = *reinterpret_cast<const bf16x8*>(Brow + (size_t)row * NC + c0 + cb);
      }
    }
#pragma unroll
    for (int kk = 0; kk < 2; kk++) {
      int kbyte = kk * 64 + lhi * 16;
      bf16x8 af[4], bfr[4];
#pragma unroll
      for (int m = 0; m < 4; m++) {
        int row = wm * 64 + m * 16 + l15;
        af[m] = *reinterpret_cast<const bf16x8*>(AsB + row * 128 + (kbyte ^ ((row & 7) << 4)));
      }
#pragma unroll
      for (int n = 0; n < 4; n++) {
        int row = wn * 64 + n * 16 + l15;
        bfr[n] = *reinterpret_cast<const bf16x8*>(BsB + row * 128 + (kbyte ^ ((row & 7) << 4)));
      }
#pragma unroll
      for (int m = 0; m < 4; m++)
#pragma unroll
        for (int n = 0; n < 4; n++)
          acc[m][n] = __builtin_amdgcn_mfma_f32_16x16x32_bf16(af[m], bfr[n], acc[m][n], 0, 0, 0);
    }
    __syncthreads();
  }

  char* stage = (char*)smem + wid * 8192;
#pragma unroll
  for (int m = 0; m < 4; m++) {
#pragma unroll
    for (int r = 0; r < 4; r++) {
      int lrow = m * 16 + lhi * 4 + r;
      float bval = bias[o0 + wm * 64 + lrow];
#pragma unroll
      for (int n = 0; n < 4; n++) {
        int col = n * 16 + l15;
        *reinterpret_cast<u16*>(stage + lrow * 128 + col * 2) = f2b(acc[m][n][r] + bval);
      }
    }
  }
  __syncthreads();
#pragma unroll
  for (int s = 0; s < 8; s++) {
    int row  = s * 8 + (lane >> 3);
    int colb = (lane & 7) * 8;
    uint4 v = *reinterpret_cast<const uint4*>(stage + row * 128 + colb * 2);
    size_t addr = ((size_t)b * NC + o0 + wm * 64 + row) * (size_t)NHW + n0 + wn * 64 + colb;
    *reinterpret_cast<uint4*>(&y[addr]) = v;
  }
}

// ---------------------------------------------------------------------------
// K3: transpose last two dims of (planes,128,128) bf16, 64x64 tiles, vectorized.
__global__ __launch_bounds__(256) void transpose128v(const u16* __restrict__ src,
                                                     u16* __restrict__ dst) {
  __shared__ u16 tile[64][68];       // 136B rows (8B aligned)
  int p = blockIdx.z;
  int i0 = blockIdx.y * 64, j0 = blockIdx.x * 64;
  int t = threadIdx.x;
  const u16* s = src + (size_t)p * NHW;
  u16* d = dst + (size_t)p * NHW;
#pragma unroll
  for (int q = 0; q < 2; q++) {
    int idx = t + q * 256;
    int r = idx >> 3, c8 = (idx & 7) * 8;
    uint4 v = *reinterpret_cast<const uint4*>(&s[(size_t)(i0 + r) * 128 + j0 + c8]);
    *reinterpret_cast<uint2*>(&tile[r][c8])     = make_uint2(v.x, v.y);
    *reinterpret_cast<uint2*>(&tile[r][c8 + 4]) = make_uint2(v.z, v.w);
  }
  __syncthreads();
#pragma unroll
  for (int q = 0; q < 2; q++) {
    int idx = t + q * 256;
    int j = idx >> 3, c8 = (idx & 7) * 8;
    u16 f[8];
#pragma unroll
    for (int v = 0; v < 8; v++) f[v] = tile[c8 + v][j];
    uint4 o;
    o.x = (uint32_t)f[0] | ((uint32_t)f[1] << 16);
    o.y = (uint32_t)f[2] | ((uint32_t)f[3] << 16);
    o.z = (uint32_t)f[4] | ((uint32_t)f[5] << 16);
    o.w = (uint32_t)f[6] | ((uint32_t)f[7] << 16);
    *reinterpret_cast<uint4*>(&d[(size_t)(j0 + j) * 128 + i0 + c8]) = o;
  }
}

// ---------------------------------------------------------------------------
// K4: BOTH energies via MFMA in one launch. grid (128, 4, 2): z = isH.
__global__ __launch_bounds__(256) void energy2(const u16* __restrict__ QT,
                                               const u16* __restrict__ KT,
                                               u16* __restrict__ att) {
  __shared__ __align__(16) u16 smem[16384];
  char* AsB = (char*)smem;
  char* BsB = (char*)(smem + 8192);
  int s = blockIdx.x, b = blockIdx.y, isH = blockIdx.z;
  int t = threadIdx.x;
  int wid = t >> 6, lane = t & 63;
  int wm = wid >> 1, wn = wid & 1;
  int l15 = lane & 15, lhi = lane >> 4;

  size_t base = (size_t)b * NHW * 64;
  size_t rowstride = isH ? (size_t)128 * 64 : 64;
  size_t off0 = isH ? (size_t)s * 64 : (size_t)s * 128 * 64;

  f32x4 acc[4][4];
#pragma unroll
  for (int m = 0; m < 4; m++)
#pragma unroll
    for (int n = 0; n < 4; n++)
#pragma unroll
      for (int r = 0; r < 4; r++) acc[m][n][r] = 0.f;

#pragma unroll
  for (int p = 0; p < 4; p++) {
    int idx = t + p * 256;
    int row = idx >> 3;
    int cb  = (idx & 7) * 8;
    int dst = row * 128 + ((cb * 2) ^ ((row & 7) << 4));
    bf16x8 av = *reinterpret_cast<const bf16x8*>(QT + base + off0 + (size_t)row * rowstride + cb);
    *reinterpret_cast<bf16x8*>(AsB + dst) = av;
    bf16x8 bv = *reinterpret_cast<const bf16x8*>(KT + base + off0 + (size_t)row * rowstride + cb);
    *reinterpret_cast<bf16x8*>(BsB + dst) = bv;
  }
  __syncthreads();
#pragma unroll
  for (int kk = 0; kk < 2; kk++) {
    int kbyte = kk * 64 + lhi * 16;
    bf16x8 af[4], bfr[4];
#pragma unroll
    for (int m = 0; m < 4; m++) {
      int row = wm * 64 + m * 16 + l15;
      af[m] = *reinterpret_cast<const bf16x8*>(AsB + row * 128 + (kbyte ^ ((row & 7) << 4)));
    }
#pragma unroll
    for (int n = 0; n < 4; n++) {
      int row = wn * 64 + n * 16 + l15;
      bfr[n] = *reinterpret_cast<const bf16x8*>(BsB + row * 128 + (kbyte ^ ((row & 7) << 4)));
    }
#pragma unroll
    for (int m = 0; m < 4; m++)
#pragma unroll
      for (int n = 0; n < 4; n++)
        acc[m][n] = __builtin_amdgcn_mfma_f32_16x16x32_bf16(af[m], bfr[n], acc[m][n], 0, 0, 0);
  }
  __syncthreads();

  char* stage = (char*)smem + wid * 8192;
#pragma unroll
  for (int m = 0; m < 4; m++) {
#pragma unroll
    for (int r = 0; r < 4; r++) {
      int lrow = m * 16 + lhi * 4 + r;
      int grow = wm * 64 + lrow;
#pragma unroll
      for (int n = 0; n < 4; n++) {
        int col = n * 16 + l15;
        int gcol = wn * 64 + col;
        float v = acc[m][n][r];
        if (isH && gcol == grow) v = -1e30f;
        *reinterpret_cast<u16*>(stage + lrow * 128 + col * 2) = f2b(v);
      }
    }
  }
  __syncthreads();
  size_t attb = (size_t)b * 4194304;
#pragma unroll
  for (int sb = 0; sb < 8; sb++) {
    int row  = wm * 64 + sb * 8 + (lane >> 3);
    int colb = wn * 64 + (lane & 7) * 8;
    uint4 v = *reinterpret_cast<const uint4*>(stage + (sb * 8 + (lane >> 3)) * 128 + (lane & 7) * 16);
    size_t addr = attb + (isH ? ((size_t)row * 32768 + (size_t)s * 256 + colb)
                              : ((size_t)s * 32768 + (size_t)row * 256 + 128 + colb));
    *reinterpret_cast<uint4*>(&att[addr]) = v;
  }
}

// ---------------------------------------------------------------------------
// K5: softmax over 256-entry rows, in place. 32 lanes per row, 8 rows/block.
__global__ __launch_bounds__(256) void softmax_kern(u16* __restrict__ att) {
  int half = threadIdx.x >> 5;        // 0..7
  int lane = threadIdx.x & 31;
  size_t row = (size_t)blockIdx.x * 8 + half;
  u16* p = att + row * 256;
  uint4 u = *reinterpret_cast<const uint4*>(&p[lane * 8]);
  float v[8]; unpack8bf(u, v);
  float mx = v[0];
  for (int i = 1; i < 8; i++) mx = fmaxf(mx, v[i]);
  for (int off = 16; off; off >>= 1) mx = fmaxf(mx, __shfl_xor(mx, off));
  float sum = 0.f;
  for (int i = 0; i < 8; i++) { v[i] = __expf(v[i] - mx); sum += v[i]; }
  for (int off = 16; off; off >>= 1) sum += __shfl_xor(sum, off);
  float inv = 1.f / sum;
  for (int i = 0; i < 8; i++) v[i] *= inv;
  *reinterpret_cast<uint4*>(&p[lane * 8]) = pack8bf(v);
}

// ---------------------------------------------------------------------------
// K6: BOTH output GEMMs via MFMA, in-place, pipelined + XCD-chunked swizzle.
// grid (4, 128, 8) = 4096 wg; logical = (lin%8)*512 + lin/8.
__global__ __launch_bounds__(256) void out_gemm2(const u16* __restrict__ Vn,
                                                 const u16* __restrict__ Vsw,
                                                 const u16* __restrict__ att) {
  __shared__ __align__(16) u16 smem[16384];
  char* AsB = (char*)smem;
  char* BsB = (char*)(smem + 8192);
  int lin = blockIdx.x + (blockIdx.y << 2) + (blockIdx.z << 9);
  int l = ((lin & 7) << 9) + (lin >> 3);     // bijective: 4096 % 8 == 0
  int ct = l & 3, s = (l >> 2) & 127, zz = l >> 9;
  int b = zz & 3, isH = zz >> 2;
  const u16* V = isH ? Vsw : Vn;
  u16* out = const_cast<u16*>(V);          // in-place (each block owns its tile)
  int t = threadIdx.x;
  int wid = t >> 6, lane = t & 63;
  int wm = wid >> 1, wn = wid & 1;
  int l15 = lane & 15, lhi = lane >> 4;

  f32x4 acc[4][4];
#pragma unroll
  for (int m = 0; m < 4; m++)
#pragma unroll
    for (int n = 0; n < 4; n++)
#pragma unroll
      for (int r = 0; r < 4; r++) acc[m][n][r] = 0.f;

  const u16* Abase = V + ((size_t)(b * NC + ct * 128)) * NHW + (size_t)s * 128;
  size_t attb = (size_t)b * 4194304;
  size_t bbase = attb + (isH ? (size_t)s * 256 : (size_t)s * 32768 + 128);
  size_t bstride = isH ? 32768 : 256;

  bf16x8 ar[4], br[4];
#pragma unroll
  for (int p = 0; p < 4; p++) {
    int idx = t + p * 256;
    int row = idx >> 3, cb = (idx & 7) * 8;
    ar[p] = *reinterpret_cast<const bf16x8*>(Abase + (size_t)row * NHW + cb);
    br[p] = *reinterpret_cast<const bf16x8*>(att + bbase + (size_t)row * bstride + cb);
  }

  for (int tt = 0; tt < 2; tt++) {
#pragma unroll
    for (int p = 0; p < 4; p++) {
      int idx = t + p * 256;
      int row = idx >> 3, cb = (idx & 7) * 8;
      int dst = row * 128 + ((cb * 2) ^ ((row & 7) << 4));
      *reinterpret_cast<bf16x8*>(AsB + dst) = ar[p];
      *reinterpret_cast<bf16x8*>(BsB + dst) = br[p];
    }
    __syncthreads();
    if (tt == 0) {
#pragma unroll
      for (int p = 0; p < 4; p++) {
        int idx = t + p * 256;
        int row = idx >> 3, cb = (idx & 7) * 8;
        ar[p] = *reinterpret_cast<const bf16x8*>(Abase + (size_t)row * NHW + 64 + cb);
        br[p] = *reinterpret_cast<const bf16x8*>(att + bbase + (size_t)row * bstride + 64 + cb);
      }
    }
#pragma unroll
    for (int kk = 0; kk < 2; kk++) {
      int kbyte = kk * 64 + lhi * 16;
      bf16x8 af[4], bfr[4];
#pragma unroll
      for (int m = 0; m < 4; m++) {
        int row = wm * 64 + m * 16 + l15;
        af[m] = *reinterpret_cast<const bf16x8*>(AsB + row * 128 + (kbyte ^ ((row & 7) << 4)));
      }
#pragma unroll
      for (int n = 0; n < 4; n++) {
        int row = wn * 64 + n * 16 + l15;
        bfr[n] = *reinterpret_cast<const bf16x8*>(BsB + row * 128 + (kbyte ^ ((row & 7) << 4)));
      }
#pragma unroll
      for (int m = 0; m < 4; m++)
#pragma unroll
        for (int n = 0; n < 4; n++)
          acc[m][n] = __builtin_amdgcn_mfma_f32_16x16x32_bf16(af[m], bfr[n], acc[m][n], 0, 0, 0);
    }
    __syncthreads();
  }

  char* stage = (char*)smem + wid * 8192;
#pragma unroll
  for (int m = 0; m < 4; m++) {
#pragma unroll
    for (int r = 0; r < 4; r++) {
      int lrow = m * 16 + lhi * 4 + r;
#pragma unroll
      for (int n = 0; n < 4; n++) {
        int col = n * 16 + l15;
        *reinterpret_cast<u16*>(stage + lrow * 128 + col * 2) = f2b(acc[m][n][r]);
      }
    }
  }
  __syncthreads();
#pragma unroll
  for (int sb = 0; sb < 8; sb++) {
    int row  = sb * 8 + (lane >> 3);
    int colb = (lane & 7) * 8;
    uint4 v = *reinterpret_cast<const uint4*>(stage + row * 128 + colb * 2);
    size_t addr = ((size_t)(b * NC + ct * 128 + wm * 64 + row)) * NHW + (size_t)s * 128 + wn * 64 + colb;
    *reinterpret_cast<uint4*>(&out[addr]) = v;
  }
}

// ---------------------------------------------------------------------------
// K7: epilogue, fully vectorized (proven).
__global__ __launch_bounds__(256) void epilogue(const u16* __restrict__ outWbf,
                                                const u16* __restrict__ outHsw,
                                                const float* __restrict__ xe,
                                                const float* __restrict__ xq,
                                                const float* __restrict__ g1p,
                                                const float* __restrict__ g2p,
                                                float* __restrict__ out0,
                                                float* __restrict__ out1) {
  __shared__ float tile[32][65];      // [w][h] fp32
  int p = blockIdx.z;                 // b*512 + c
  int h0 = blockIdx.y * 64, w0 = blockIdx.x * 32;
  int t = threadIdx.x;
  {
    int w = t >> 3, hc = t & 7;
    uint4 v = *reinterpret_cast<const uint4*>(
        &outHsw[(size_t)p * NHW + (size_t)(w0 + w) * 128 + h0 + hc * 8]);
    float f[8]; unpack8bf(v, f);
    for (int j = 0; j < 8; j++) tile[w][hc * 8 + j] = f[j];
  }
  __syncthreads();
  float g1 = g1p[0], g2 = g2p[0];
  int h = t >> 2, wc = t & 3;
  size_t idx = (size_t)p * NHW + (size_t)(h0 + h) * 128 + w0 + wc * 8;
  uint4 wv = *reinterpret_cast<const uint4*>(&outWbf[idx]);
  float s[8]; unpack8bf(wv, s);
  float4 xe0 = *reinterpret_cast<const float4*>(&xe[idx]);
  float4 xe1 = *reinterpret_cast<const float4*>(&xe[idx + 4]);
  float4 xq0 = *reinterpret_cast<const float4*>(&xq[idx]);
  float4 xq1 = *reinterpret_cast<const float4*>(&xq[idx + 4]);
  float sum[8];
  for (int j = 0; j < 8; j++) sum[j] = s[j] + tile[wc * 8 + j][h] + 2.0f;
  float4 o0a = {g1 * sum[0] + xe0.x, g1 * sum[1] + xe0.y, g1 * sum[2] + xe0.z, g1 * sum[3] + xe0.w};
  float4 o0b = {g1 * sum[4] + xe1.x, g1 * sum[5] + xe1.y, g1 * sum[6] + xe1.z, g1 * sum[7] + xe1.w};
  float4 o1a = {g2 * sum[0] + xq0.x, g2 * sum[1] + xq0.y, g2 * sum[2] + xq0.z, g2 * sum[3] + xq0.w};
  float4 o1b = {g2 * sum[4] + xq1.x, g2 * sum[5] + xq1.y, g2 * sum[6] + xq1.z, g2 * sum[7] + xq1.w};
  *reinterpret_cast<float4*>(&out0[idx])     = o0a;
  *reinterpret_cast<float4*>(&out0[idx + 4]) = o0b;
  *reinterpret_cast<float4*>(&out1[idx])     = o1a;
  *reinterpret_cast<float4*>(&out1[idx + 4]) = o1b;
}

// ---------------------------------------------------------------------------
extern "C" void kernel_launch(void* const* d_in, const int* in_sizes, int n_in,
                              void* d_out, int out_size, void* d_ws, size_t ws_size,
                              hipStream_t stream) {
  (void)in_sizes; (void)n_in; (void)out_size; (void)ws_size;
  const float* xe = (const float*)d_in[0];
  const float* xq = (const float*)d_in[1];
  const float* Wq = (const float*)d_in[2];
  const float* bq = (const float*)d_in[3];
  const float* Wk = (const float*)d_in[4];
  const float* bk = (const float*)d_in[5];
  const float* Wv = (const float*)d_in[6];
  const float* bv = (const float*)d_in[7];
  const float* g1 = (const float*)d_in[8];
  const float* g2 = (const float*)d_in[9];
  float* out = (float*)d_out;

  char* ws = (char*)d_ws;
  u16* qT    = (u16*)(ws + 0);            //  8 MiB  (4,16384,64) bf16
  u16* kT    = (u16*)(ws + 8388608);      //  8 MiB
  u16* wv_bf = (u16*)(ws + 16777216);     //  512 KiB
  u16* wq_bf = (u16*)(ws + 17301504);     //  64 KiB
  u16* wk_bf = (u16*)(ws + 17367040);     //  64 KiB
  u16* v_n   = (u16*)(ws + 33554432);     // 64 MiB  (4,512,128,128) -> becomes outW bf16
  u16* v_sw  = (u16*)(ws + 100663296);    // 64 MiB  (b,c,w,h)       -> becomes outHsw bf16
  u16* att   = (u16*)(ws + 167772160);    // 32 MiB  (4,128,128,256)
  u16* xeT   = (u16*)(ws + 201326592);    // 64 MiB  (b,hw,c) bf16
  u16* xqT   = (u16*)(ws + 100663296);    // 64 MiB  in v_sw slot (v_sw written later)

  transpose_cvt2<<<dim3(256, 8, 9), 256, 0, stream>>>(xe, xq, xeT, xqT,
                                                      Wv, Wq, Wk, wv_bf, wq_bf, wk_bf);
  proj64_qk<<<dim3(128, 2, 4), 256, 0, stream>>>(xeT, xqT, wk_bf, wq_bf, bk, bq, kT, qT);
  proj_v_mfma<<<dim3(4, 128, 4), 256, 0, stream>>>(xeT, wv_bf, bv, v_n);
  transpose128v<<<dim3(2, 2, 2048), 256, 0, stream>>>(v_n, v_sw);   // overwrites xqT (dead)
  energy2<<<dim3(128, 4, 2), 256, 0, stream>>>(qT, kT, att);
  softmax_kern<<<dim3(8192), 256, 0, stream>>>(att);
  out_gemm2<<<dim3(4, 128, 8), 256, 0, stream>>>(v_n, v_sw, att);   // in-place
  epilogue<<<dim3(4, 2, 2048), 256, 0, stream>>>(v_n, v_sw, xe, xq, g1, g2,
                                                 out, out + 33554432);
}